// Round 2
// baseline (1319.651 us; speedup 1.0000x reference)
//
#include <hip/hip_runtime.h>
#include <hip/hip_bf16.h>
#include <math.h>

#define N_NODES 50000
#define NPAD    50048                  // N_NODES rounded up to 128 (gemm tiles, no guards)
#define N_EDGES 800000
#define EPRIME  (N_EDGES + N_NODES)   // edges + self loops
#define EPAD    850048                 // EPRIME rounded up to 128 (edge head, no guards)
#define HEADS 8
#define CH 64
#define FDIM 512                       // HEADS*CH

typedef unsigned short ushort_t;
typedef __attribute__((ext_vector_type(8))) short bf16x8_t;  // 8 bf16 = 4 VGPRs
typedef __attribute__((ext_vector_type(4))) float f32x4_t;

__device__ __forceinline__ float bf2f(unsigned short u) {
  union { unsigned int i; float f; } v; v.i = ((unsigned int)u) << 16; return v.f;
}
__device__ __forceinline__ unsigned short f2bf(float f) {
  union { float f; unsigned int i; } v; v.f = f;
  unsigned int x = v.i;
  return (unsigned short)((x + 0x7fffu + ((x >> 16) & 1u)) >> 16);  // RNE
}
__device__ __forceinline__ float ldf(const void* p, size_t idx, int isf32) {
  return isf32 ? ((const float*)p)[idx] : bf2f(((const ushort_t*)p)[idx]);
}
__device__ __forceinline__ void stf(void* p, size_t idx, float v, int isf32) {
  if (isf32) ((float*)p)[idx] = v;
  else       ((ushort_t*)p)[idx] = f2bf(v);
}
__device__ __forceinline__ float leakyf(float v) { return v >= 0.f ? v : 0.2f * v; }
__device__ __forceinline__ float eluf(float v)   { return v > 0.f ? v : expm1f(v); }

// async global->LDS, 16B per lane; LDS dest = wave-uniform base + lane*16
typedef const __attribute__((address_space(1))) unsigned int* gas1_t;
typedef __attribute__((address_space(3))) unsigned int* las3_t;
__device__ __forceinline__ void gll16(const ushort_t* g, ushort_t* l) {
  __builtin_amdgcn_global_load_lds((gas1_t)g, (las3_t)l, 16, 0, 0);
}

// ---------------- dtype detector ----------------
__global__ void detect_dtype(const void* Wn, int* flag) {
  if (blockIdx.x == 0 && threadIdx.x == 0) {
    const ushort_t* u = (const ushort_t*)Wn;
    int extreme = 0;
    for (int i = 0; i < 384; ++i) {
      float v = fabsf(bf2f(u[i]));
      if (v != 0.f && (v > 16.f || v < 6.1e-5f)) extreme++;
    }
    *flag = (extreme >= 20) ? 1 : 0;
  }
}

// ---------------- weight transpose-convert: dst[n*K+k] = src[(boff+k)*N + n] ----
__global__ void convert_wt(const void* __restrict__ src, ushort_t* __restrict__ dst,
                           int K, int N, int boff, const int* __restrict__ dflag) {
  int isf32 = *dflag;
  int tid = blockIdx.x * blockDim.x + threadIdx.x;
  if (tid >= N * K) return;
  int n = tid / K, k = tid % K;
  dst[tid] = f2bf(ldf(src, (size_t)(boff + k) * N + n, isf32));
}

// pack 6 attention vectors (3 layers x {a_src, a_dst}, 512 elems each) to bf16
__global__ void convert_att(const void* s1, const void* d1, const void* s2, const void* d2,
                            const void* s3, const void* d3, ushort_t* __restrict__ dst,
                            const int* __restrict__ dflag) {
  int isf32 = *dflag;
  int tid = blockIdx.x * blockDim.x + threadIdx.x;
  if (tid >= 6 * 512) return;
  int which = tid >> 9, idx = tid & 511;
  const void* p = which == 0 ? s1 : which == 1 ? d1 : which == 2 ? s2
                : which == 3 ? d2 : which == 4 ? s3 : d3;
  dst[tid] = f2bf(ldf(p, idx, isf32));
}

// ---------------- CSR build ----------------
__global__ void init_deg(int* deg, int* fill) {
  int n = blockIdx.x * blockDim.x + threadIdx.x;
  if (n < N_NODES) { deg[n] = 1; fill[n] = 0; }   // 1 = self loop
}

__global__ void count_edges(const int* __restrict__ ei, int* deg) {
  int e = blockIdx.x * blockDim.x + threadIdx.x;
  if (e < N_EDGES) atomicAdd(&deg[ei[N_EDGES + e]], 1);
}

__global__ void scan64(const int* __restrict__ deg, int* __restrict__ rowptr) {
  const int CHUNK = (N_NODES + 63) / 64;   // 782
  int t = threadIdx.x;
  int lo = t * CHUNK;
  int hi = lo + CHUNK; if (hi > N_NODES) hi = N_NODES;
  int s = 0;
  for (int i = lo; i < hi; ++i) s += deg[i];
  int inc = s;
  #pragma unroll
  for (int off = 1; off < 64; off <<= 1) {
    int u = __shfl_up(inc, off);
    if (t >= off) inc += u;
  }
  int run = inc - s;
  for (int i = lo; i < hi; ++i) { rowptr[i] = run; run += deg[i]; }
  if (t == 63) rowptr[N_NODES] = run;
}

// also writes csr_dst (dst per CSR slot) and csr_eid (original edge id, -1 for
// self loops); pads [EPRIME, EPAD) with harmless sentinel entries.
__global__ void fill_csr(const int* __restrict__ ei, const int* __restrict__ rowptr,
                         int* fill, int* __restrict__ csr_src,
                         int* __restrict__ csr_dst, int* __restrict__ csr_eid) {
  int e = blockIdx.x * blockDim.x + threadIdx.x;
  if (e >= EPAD) return;
  if (e >= EPRIME) {                     // pad slots live past every rowptr fill
    csr_src[e] = 0; csr_dst[e] = 0; csr_eid[e] = -1;
    return;
  }
  int s, d, id;
  if (e < N_EDGES) { s = ei[e]; d = ei[N_EDGES + e]; id = e; }
  else             { s = d = e - N_EDGES; id = -1; }   // self loop: no edge output
  int pos = rowptr[d] + atomicAdd(&fill[d], 1);
  csr_src[pos] = s;
  csr_dst[pos] = d;
  csr_eid[pos] = id;
}

// ---------------- node encoder ----------------
__global__ void encode_h(const void* __restrict__ x, const void* __restrict__ Wn,
                         const void* __restrict__ bn, ushort_t* __restrict__ h,
                         const int* __restrict__ dflag) {
  int isf32 = *dflag;
  int tid = blockIdx.x * blockDim.x + threadIdx.x;
  if (tid >= N_NODES * 64) return;
  int n = tid >> 6, j = tid & 63;
  float x0 = ldf(x, n * 3 + 0, isf32), x1 = ldf(x, n * 3 + 1, isf32), x2 = ldf(x, n * 3 + 2, isf32);
  float v = x0 * ldf(Wn, j, isf32) + x1 * ldf(Wn, 64 + j, isf32)
          + x2 * ldf(Wn, 128 + j, isf32) + ldf(bn, j, isf32);
  h[tid] = f2bf(v);
}

// ---------------- MFMA GEMM + fused attn-coef epilogue ------------------------
// C = A @ BT^T.  When att != nullptr (layer gemms, 128-col block = 2 heads,
// wave covers exactly one head = 2*by + wc), the epilogue computes
// asrc/adst[row,head] = dot(C_row_head, a_src/a_dst) via 16-lane reduce.
__global__ __launch_bounds__(256) void gemm_bt(
    const ushort_t* __restrict__ A, const ushort_t* __restrict__ BT,
    ushort_t* __restrict__ C, int K, int ldc,
    const ushort_t* __restrict__ att, float* __restrict__ asrc, float* __restrict__ adst)
{
  __shared__ __align__(16) ushort_t As[128][32];
  __shared__ __align__(16) ushort_t Bs[128][32];
  int tid = threadIdx.x;
  int wave = tid >> 6, lane = tid & 63;
  int wr = wave >> 1, wc = wave & 1;
  int row0 = blockIdx.x * 128, col0 = blockIdx.y * 128;
  int fm = lane & 15, fq = lane >> 4;

  f32x4_t acc[4][4];
  #pragma unroll
  for (int i = 0; i < 4; ++i)
    #pragma unroll
    for (int j = 0; j < 4; ++j) acc[i][j] = (f32x4_t){0.f, 0.f, 0.f, 0.f};

  int srow = wave * 32 + (lane >> 2);
  int skel = (lane & 3) * 8;
  const ushort_t* aG0 = A  + (size_t)(row0 + srow) * K + skel;
  const ushort_t* aG1 = A  + (size_t)(row0 + srow + 16) * K + skel;
  const ushort_t* bG0 = BT + (size_t)(col0 + srow) * K + skel;
  const ushort_t* bG1 = BT + (size_t)(col0 + srow + 16) * K + skel;
  ushort_t* aL0 = &As[wave * 32][0];
  ushort_t* aL1 = &As[wave * 32 + 16][0];
  ushort_t* bL0 = &Bs[wave * 32][0];
  ushort_t* bL1 = &Bs[wave * 32 + 16][0];

  for (int k0 = 0; k0 < K; k0 += 32) {
    gll16(aG0 + k0, aL0);
    gll16(aG1 + k0, aL1);
    gll16(bG0 + k0, bL0);
    gll16(bG1 + k0, bL1);
    __syncthreads();
    bf16x8_t af[4], bfr[4];
    #pragma unroll
    for (int i = 0; i < 4; ++i) af[i]  = *(const bf16x8_t*)&As[64 * wr + 16 * i + fm][fq * 8];
    #pragma unroll
    for (int j = 0; j < 4; ++j) bfr[j] = *(const bf16x8_t*)&Bs[64 * wc + 16 * j + fm][fq * 8];
    #pragma unroll
    for (int i = 0; i < 4; ++i)
      #pragma unroll
      for (int j = 0; j < 4; ++j)
        acc[i][j] = __builtin_amdgcn_mfma_f32_16x16x32_bf16(af[i], bfr[j], acc[i][j], 0, 0, 0);
    __syncthreads();
  }

  int do_att = (att != nullptr);
  int head = 2 * blockIdx.y + wc;
  float sa[4], sd[4];
  if (do_att) {
    #pragma unroll
    for (int j = 0; j < 4; ++j) {
      int ch = 16 * j + fm;
      sa[j] = bf2f(att[head * CH + ch]);
      sd[j] = bf2f(att[512 + head * CH + ch]);
    }
  }

  // C/D layout: col = lane&15, row = (lane>>4)*4 + reg
  #pragma unroll
  for (int i = 0; i < 4; ++i) {
    int rowb = row0 + 64 * wr + 16 * i + fq * 4;
    #pragma unroll
    for (int r = 0; r < 4; ++r) {
      int row = rowb + r;
      float ss = 0.f, dd = 0.f;
      #pragma unroll
      for (int j = 0; j < 4; ++j) {
        ushort_t uv = f2bf(acc[i][j][r]);
        C[(size_t)row * ldc + col0 + 64 * wc + 16 * j + fm] = uv;
        if (do_att) {
          float cv = bf2f(uv);
          ss += cv * sa[j];
          dd += cv * sd[j];
        }
      }
      if (do_att) {
        #pragma unroll
        for (int off = 8; off > 0; off >>= 1) {
          ss += __shfl_down(ss, off);
          dd += __shfl_down(dd, off);
        }
        if (fm == 0 && row < N_NODES) {
          asrc[row * HEADS + head] = ss;
          adst[row * HEADS + head] = dd;
        }
      }
    }
  }
}

// ---------------- maxless-softmax aggregation (gather per dst), unroll x8 -----
// thread t -> channels (2t, 2t+1), head t>>5.
// mean_mode=0: out[n,512] = bf16(elu(acc + bc) + (x@Wr + br)[n])
// mean_mode=1: out[n,64]  = bf16(elu(mean_h(acc) + bc)); fused node head -> outh
// sumv stores the RECIPROCAL 1/l (consumed only by edge_head as a multiply).
__global__ __launch_bounds__(256) void aggregate(
    const int* __restrict__ rowptr, const int* __restrict__ csr_src,
    const float* __restrict__ asrc, const float* __restrict__ adst,
    float* __restrict__ sumv,
    const ushort_t* __restrict__ g,
    const void* __restrict__ x, const void* __restrict__ Wr,
    const void* __restrict__ br, const void* __restrict__ bc,
    ushort_t* __restrict__ out, int mean_mode,
    const void* __restrict__ Wo, const void* __restrict__ bo,
    void* __restrict__ outh, const int* __restrict__ dflag)
{
  int isf32 = *dflag;
  __shared__ float sx[3];
  int n = blockIdx.x;
  int t = threadIdx.x;
  if (t < 3) sx[t] = ldf(x, n * 3 + t, isf32);
  __syncthreads();

  int start = rowptr[n], end = rowptr[n + 1];
  int c0 = t * 2;
  int h  = t >> 5;
  int i0 = n * HEADS + h;
  float ad = adst[i0];

  float l = 0.f, a0 = 0.f, a1 = 0.f;
  int i = start;
  for (; i + 8 <= end; i += 8) {
    int s[8];
    #pragma unroll
    for (int k = 0; k < 8; ++k) s[k] = csr_src[i + k];
    float e[8];
    unsigned int gv[8];
    #pragma unroll
    for (int k = 0; k < 8; ++k) {
      e[k]  = asrc[s[k] * HEADS + h] + ad;
      gv[k] = *(const unsigned int*)(g + (size_t)s[k] * FDIM + c0);
    }
    #pragma unroll
    for (int k = 0; k < 8; ++k) {
      float p = __expf(leakyf(e[k]));
      l  += p;
      a0 += p * bf2f((ushort_t)(gv[k] & 0xffffu));
      a1 += p * bf2f((ushort_t)(gv[k] >> 16));
    }
  }
  for (; i + 2 <= end; i += 2) {
    int s0 = csr_src[i], s1 = csr_src[i + 1];
    float e0 = asrc[s0 * HEADS + h] + ad;
    float e1 = asrc[s1 * HEADS + h] + ad;
    unsigned int g0 = *(const unsigned int*)(g + (size_t)s0 * FDIM + c0);
    unsigned int g1 = *(const unsigned int*)(g + (size_t)s1 * FDIM + c0);
    float p0 = __expf(leakyf(e0)), p1 = __expf(leakyf(e1));
    l  += p0 + p1;
    a0 += p0 * bf2f((ushort_t)(g0 & 0xffffu)) + p1 * bf2f((ushort_t)(g1 & 0xffffu));
    a1 += p0 * bf2f((ushort_t)(g0 >> 16))     + p1 * bf2f((ushort_t)(g1 >> 16));
  }
  if (i < end) {
    int s0 = csr_src[i];
    float p0 = __expf(leakyf(asrc[s0 * HEADS + h] + ad));
    unsigned int g0 = *(const unsigned int*)(g + (size_t)s0 * FDIM + c0);
    l  += p0;
    a0 += p0 * bf2f((ushort_t)(g0 & 0xffffu));
    a1 += p0 * bf2f((ushort_t)(g0 >> 16));
  }
  a0 /= l;
  a1 /= l;
  if ((t & 31) == 0) sumv[i0] = 1.f / l;   // reciprocal; one writer per (node,head)

  if (!mean_mode) {
    float r0 = sx[0] * ldf(Wr, c0, isf32)         + sx[1] * ldf(Wr, 512 + c0, isf32)
             + sx[2] * ldf(Wr, 1024 + c0, isf32)  + ldf(br, c0, isf32);
    float r1 = sx[0] * ldf(Wr, c0 + 1, isf32)     + sx[1] * ldf(Wr, 512 + c0 + 1, isf32)
             + sx[2] * ldf(Wr, 1024 + c0 + 1, isf32) + ldf(br, c0 + 1, isf32);
    unsigned int o0 = f2bf(eluf(a0 + ldf(bc, c0, isf32)) + r0);
    unsigned int o1 = f2bf(eluf(a1 + ldf(bc, c0 + 1, isf32)) + r1);
    *(unsigned int*)(out + (size_t)n * FDIM + c0) = o0 | (o1 << 16);
  } else {
    __shared__ float red[512];
    red[c0] = a0; red[c0 + 1] = a1;
    __syncthreads();
    if (t < 64) {                               // wave 0, uniform branch
      float tot = 0.f;
      #pragma unroll
      for (int hh = 0; hh < 8; ++hh) tot += red[t + 64 * hh];
      ushort_t uv = f2bf(eluf(tot * 0.125f + ldf(bc, t, isf32)));
      out[(size_t)n * CH + t] = uv;
      // fused node head on the bf16-rounded ne value (matches old node_head)
      float nv = bf2f(uv);
      float p0 = nv * ldf(Wo, t * 2 + 0, isf32);
      float p1 = nv * ldf(Wo, t * 2 + 1, isf32);
      float vv = (t & 1) ? p1 : p0;
      float ww = (t & 1) ? p0 : p1;
      vv += __shfl_xor(ww, 1);
      #pragma unroll
      for (int off = 2; off < 64; off <<= 1) vv += __shfl_xor(vv, off);
      if (t < 2) stf(outh, (size_t)n * 2 + t, vv + ldf(bo, t, isf32), isf32);
    }
  }
}

// ---------------- edge head v5: flat over CSR order, fixed trip count ---------
// Wave processes 32 consecutive CSR slots (2-edge pipeline, 16 fixed iters).
// CSR order groups same-dst edges (~17-long runs) so Q-row / adst / rsumv
// gathers are cache hits; rsumv is a precomputed reciprocal (no division).
// Self-loop and pad slots carry eid=-1: computed, not stored.
#define EPW 32
__global__ __launch_bounds__(256) void edge_head5(
    const int* __restrict__ csr_src, const int* __restrict__ csr_dst,
    const int* __restrict__ csr_eid,
    const float* __restrict__ asrc, const float* __restrict__ adst,
    const float* __restrict__ rsumv,
    const ushort_t* __restrict__ pq, const void* __restrict__ Wm1,
    const void* __restrict__ bm1, const void* __restrict__ Wm2,
    const void* __restrict__ bm2, void* __restrict__ out,
    const int* __restrict__ dflag)
{
  int isf32 = *dflag;
  int lane = threadIdx.x & 63;
  int c0 = lane * 4;
  int h = lane & 7;
  float w1r[8][4], w2a[4], w2b[4], b1r[4];
  #pragma unroll
  for (int hh = 0; hh < 8; ++hh)
    #pragma unroll
    for (int j = 0; j < 4; ++j)
      w1r[hh][j] = ldf(Wm1, (64 + hh) * 256 + c0 + j, isf32);
  #pragma unroll
  for (int j = 0; j < 4; ++j) {
    w2a[j] = ldf(Wm2, (c0 + j) * 2 + 0, isf32);
    w2b[j] = ldf(Wm2, (c0 + j) * 2 + 1, isf32);
    b1r[j] = ldf(bm1, c0 + j, isf32);
  }
  float bo0 = ldf(bm2, 0, isf32), bo1 = ldf(bm2, 1, isf32);

  int wid = blockIdx.x * 4 + (threadIdx.x >> 6);
  int e0 = wid * EPW;                       // EPW*4=128 divides EPAD exactly
  for (int e = e0; e < e0 + EPW; e += 2) {
    int sA = csr_src[e],     sB = csr_src[e + 1];
    int dA = csr_dst[e],     dB = csr_dst[e + 1];
    int eA = csr_eid[e],     eB = csr_eid[e + 1];
    float vA = asrc[sA * HEADS + h] + adst[dA * HEADS + h];
    float vB = asrc[sB * HEADS + h] + adst[dB * HEADS + h];
    float rsA = rsumv[dA * HEADS + h], rsB = rsumv[dB * HEADS + h];
    ushort4 pvA = *(const ushort4*)(pq + (size_t)sA * FDIM + c0);
    ushort4 qvA = *(const ushort4*)(pq + (size_t)dA * FDIM + 256 + c0);
    ushort4 pvB = *(const ushort4*)(pq + (size_t)sB * FDIM + c0);
    ushort4 qvB = *(const ushort4*)(pq + (size_t)dB * FDIM + 256 + c0);
    float aA = __expf(leakyf(vA)) * rsA;
    float aB = __expf(leakyf(vB)) * rsB;
    float alA[8], alB[8];
    #pragma unroll
    for (int hh = 0; hh < 8; ++hh) { alA[hh] = __shfl(aA, hh); alB[hh] = __shfl(aB, hh); }

    float accA0 = 0.f, accA1 = 0.f, accB0 = 0.f, accB1 = 0.f;
    float pA[4] = { bf2f(pvA.x), bf2f(pvA.y), bf2f(pvA.z), bf2f(pvA.w) };
    float qA[4] = { bf2f(qvA.x), bf2f(qvA.y), bf2f(qvA.z), bf2f(qvA.w) };
    float pB[4] = { bf2f(pvB.x), bf2f(pvB.y), bf2f(pvB.z), bf2f(pvB.w) };
    float qB[4] = { bf2f(qvB.x), bf2f(qvB.y), bf2f(qvB.z), bf2f(qvB.w) };
    #pragma unroll
    for (int j = 0; j < 4; ++j) {
      float hvA = pA[j] + qA[j] + b1r[j];
      float hvB = pB[j] + qB[j] + b1r[j];
      #pragma unroll
      for (int hh = 0; hh < 8; ++hh) {
        hvA += alA[hh] * w1r[hh][j];
        hvB += alB[hh] * w1r[hh][j];
      }
      hvA = fmaxf(hvA, 0.f);
      hvB = fmaxf(hvB, 0.f);
      accA0 += hvA * w2a[j]; accA1 += hvA * w2b[j];
      accB0 += hvB * w2a[j]; accB1 += hvB * w2b[j];
    }
    #pragma unroll
    for (int off = 32; off > 0; off >>= 1) {
      accA0 += __shfl_down(accA0, off);
      accA1 += __shfl_down(accA1, off);
      accB0 += __shfl_down(accB0, off);
      accB1 += __shfl_down(accB1, off);
    }
    if (lane == 0) {
      if (eA >= 0) {
        stf(out, 100000 + (size_t)eA * 2 + 0, accA0 + bo0, isf32);
        stf(out, 100000 + (size_t)eA * 2 + 1, accA1 + bo1, isf32);
      }
      if (eB >= 0) {
        stf(out, 100000 + (size_t)eB * 2 + 0, accB0 + bo0, isf32);
        stf(out, 100000 + (size_t)eB * 2 + 1, accB1 + bo1, isf32);
      }
    }
  }
}

// ---------------- launch ----------------
extern "C" void kernel_launch(void* const* d_in, const int* in_sizes, int n_in,
                              void* d_out, int out_size, void* d_ws, size_t ws_size,
                              hipStream_t stream) {
  const void* x   = d_in[0];
  const int*  ei  = (const int*)d_in[1];
  const void* Wn  = d_in[4];
  const void* bn  = d_in[5];
  const void* Wr  = d_in[6];
  const void* br  = d_in[7];
  const void* W1  = d_in[8];
  const void* as1 = d_in[9];
  const void* ad1 = d_in[10];
  const void* bc1 = d_in[11];
  const void* W2  = d_in[12];
  const void* as2 = d_in[13];
  const void* ad2 = d_in[14];
  const void* bc2 = d_in[15];
  const void* W3  = d_in[16];
  const void* as3 = d_in[17];
  const void* ad3 = d_in[18];
  const void* bc3 = d_in[19];
  const void* Wo  = d_in[20];
  const void* bo  = d_in[21];
  const void* Wm1 = d_in[22];
  const void* bm1 = d_in[23];
  const void* Wm2 = d_in[24];
  const void* bm2 = d_in[25];

  char* ws = (char*)d_ws;
  size_t off = 0;
  auto take = [&](size_t bytes) -> char* {
    char* p = ws + off;
    off += (bytes + 255) & ~(size_t)255;
    return p;
  };
  ushort_t* h_bf   = (ushort_t*)take((size_t)NPAD * 64 * 2);       // enc out / node_embedding
  ushort_t* g_bf   = (ushort_t*)take((size_t)NPAD * FDIM * 2);     // gemm out / P|Q
  ushort_t* o_bf   = (ushort_t*)take((size_t)NPAD * FDIM * 2);     // layer out
  float*    asrc   = (float*)take((size_t)N_NODES * HEADS * 4);
  float*    adst   = (float*)take((size_t)N_NODES * HEADS * 4);
  float*    sumv   = (float*)take((size_t)N_NODES * HEADS * 4);
  int*      rowptr = (int*)take((size_t)(N_NODES + 1) * 4);
  int*      csr_src= (int*)take((size_t)EPAD * 4);
  int*      csr_dst= (int*)take((size_t)EPAD * 4);
  int*      csr_eid= (int*)take((size_t)EPAD * 4);
  int*      deg    = (int*)take((size_t)N_NODES * 4);
  int*      fillc  = (int*)take((size_t)N_NODES * 4);
  int*      dflag  = (int*)take(256);
  ushort_t* WT1    = (ushort_t*)take((size_t)512 * 64 * 2);        // W1^T  [512][64]
  ushort_t* WT2    = (ushort_t*)take((size_t)512 * 512 * 2);       // W2^T  [512][512]
  ushort_t* WT3    = (ushort_t*)take((size_t)512 * 512 * 2);       // W3^T  [512][512]
  ushort_t* WTPQ   = (ushort_t*)take((size_t)512 * 64 * 2);        // [P^T ; Q^T] combined
  ushort_t* attv   = (ushort_t*)take((size_t)6 * 512 * 2);         // packed a_src/a_dst x3

  dim3 b256(256);
  const int MB = NPAD / 128;  // 391

  detect_dtype<<<dim3(1), dim3(64), 0, stream>>>(Wn, dflag);

  // weight conversion (transpose to [n][k], bf16); W1 is [64,512] -> K=64
  convert_wt<<<dim3(128),  b256, 0, stream>>>(W1, WT1, 64, 512, 0, dflag);
  convert_wt<<<dim3(1024), b256, 0, stream>>>(W2, WT2, 512, 512, 0, dflag);
  convert_wt<<<dim3(1024), b256, 0, stream>>>(W3, WT3, 512, 512, 0, dflag);
  convert_wt<<<dim3(64),   b256, 0, stream>>>(Wm1, WTPQ,            64, 256, 0,  dflag);
  convert_wt<<<dim3(64),   b256, 0, stream>>>(Wm1, WTPQ + 256 * 64, 64, 256, 72, dflag);
  convert_att<<<dim3(12),  b256, 0, stream>>>(as1, ad1, as2, ad2, as3, ad3, attv, dflag);

  // CSR build
  init_deg<<<dim3((N_NODES + 255) / 256), b256, 0, stream>>>(deg, fillc);
  count_edges<<<dim3((N_EDGES + 255) / 256), b256, 0, stream>>>(ei, deg);
  scan64<<<dim3(1), dim3(64), 0, stream>>>(deg, rowptr);
  fill_csr<<<dim3((EPAD + 255) / 256), b256, 0, stream>>>(ei, rowptr, fillc,
                                                          csr_src, csr_dst, csr_eid);

  // node encoder
  encode_h<<<dim3((N_NODES * 64 + 255) / 256), b256, 0, stream>>>(x, Wn, bn, h_bf, dflag);

  // ---- GAT layer 1 (in: h_bf [NPAD,64]); attn fused in gemm epilogue ----
  gemm_bt<<<dim3(MB, 4), b256, 0, stream>>>(h_bf, WT1, g_bf, 64, 512,
                                            attv, asrc, adst);
  aggregate<<<dim3(N_NODES), b256, 0, stream>>>(rowptr, csr_src, asrc, adst, sumv,
                                                g_bf, x, Wr, br, bc1, o_bf, 0,
                                                nullptr, nullptr, d_out, dflag);

  // ---- GAT layer 2 ----
  gemm_bt<<<dim3(MB, 4), b256, 0, stream>>>(o_bf, WT2, g_bf, 512, 512,
                                            attv + 1024, asrc, adst);
  aggregate<<<dim3(N_NODES), b256, 0, stream>>>(rowptr, csr_src, asrc, adst, sumv,
                                                g_bf, x, Wr, br, bc2, o_bf, 0,
                                                nullptr, nullptr, d_out, dflag);

  // ---- GAT layer 3 (mean over heads -> ne in h_bf; node head fused) ----
  gemm_bt<<<dim3(MB, 4), b256, 0, stream>>>(o_bf, WT3, g_bf, 512, 512,
                                            attv + 2048, asrc, adst);
  aggregate<<<dim3(N_NODES), b256, 0, stream>>>(rowptr, csr_src, asrc, adst, sumv,
                                                g_bf, x, Wr, br, bc3, h_bf, 1,
                                                Wo, bo, d_out, dflag);

  // ---- edge head: P|Q in one gemm, then CSR-ordered per-edge MLP ----
  gemm_bt<<<dim3(MB, 4), b256, 0, stream>>>(h_bf, WTPQ, g_bf, 64, 512,
                                            nullptr, nullptr, nullptr);
  edge_head5<<<dim3(EPAD / (EPW * 4)), b256, 0, stream>>>(csr_src, csr_dst, csr_eid,
                                                          asrc, adst, sumv, g_bf,
                                                          Wm1, bm1, Wm2, bm2,
                                                          d_out, dflag);
}

// Round 3
// 1199.828 us; speedup vs baseline: 1.0999x; 1.0999x over previous
//
#include <hip/hip_runtime.h>
#include <hip/hip_bf16.h>
#include <math.h>

#define N_NODES 50000
#define NPAD    50048                  // N_NODES rounded up to 128 (gemm tiles, no guards)
#define N_EDGES 800000
#define EPRIME  (N_EDGES + N_NODES)   // edges + self loops
#define HEADS 8
#define CH 64
#define FDIM 512                       // HEADS*CH

typedef unsigned short ushort_t;
typedef __attribute__((ext_vector_type(8))) short bf16x8_t;  // 8 bf16 = 4 VGPRs
typedef __attribute__((ext_vector_type(4))) float f32x4_t;

__device__ __forceinline__ float bf2f(unsigned short u) {
  union { unsigned int i; float f; } v; v.i = ((unsigned int)u) << 16; return v.f;
}
__device__ __forceinline__ unsigned short f2bf(float f) {
  union { float f; unsigned int i; } v; v.f = f;
  unsigned int x = v.i;
  return (unsigned short)((x + 0x7fffu + ((x >> 16) & 1u)) >> 16);  // RNE
}
__device__ __forceinline__ float ldf(const void* p, size_t idx, int isf32) {
  return isf32 ? ((const float*)p)[idx] : bf2f(((const ushort_t*)p)[idx]);
}
__device__ __forceinline__ void stf(void* p, size_t idx, float v, int isf32) {
  if (isf32) ((float*)p)[idx] = v;
  else       ((ushort_t*)p)[idx] = f2bf(v);
}
__device__ __forceinline__ float leakyf(float v) { return v >= 0.f ? v : 0.2f * v; }
__device__ __forceinline__ float eluf(float v)   { return v > 0.f ? v : expm1f(v); }

// wave64 sum via DPP butterfly (LLVM AtomicOptimizer sequence); full sum valid
// in lanes 48..63 (use lane 63). Pure VALU — no DS pipe, no LDS.
__device__ __forceinline__ float dpp_sum64(float x) {
  x += __int_as_float(__builtin_amdgcn_update_dpp(0, __float_as_int(x), 0xB1, 0xf, 0xf, false)); // quad_perm [1,0,3,2]
  x += __int_as_float(__builtin_amdgcn_update_dpp(0, __float_as_int(x), 0x4E, 0xf, 0xf, false)); // quad_perm [2,3,0,1]
  x += __int_as_float(__builtin_amdgcn_update_dpp(0, __float_as_int(x), 0x141, 0xf, 0xf, false)); // row_half_mirror
  x += __int_as_float(__builtin_amdgcn_update_dpp(0, __float_as_int(x), 0x140, 0xf, 0xf, false)); // row_mirror
  x += __int_as_float(__builtin_amdgcn_update_dpp(0, __float_as_int(x), 0x142, 0xa, 0xf, false)); // row_bcast:15 rows 1,3
  x += __int_as_float(__builtin_amdgcn_update_dpp(0, __float_as_int(x), 0x143, 0xc, 0xf, false)); // row_bcast:31 rows 2,3
  return x;
}

// async global->LDS, 16B per lane; LDS dest = wave-uniform base + lane*16
typedef const __attribute__((address_space(1))) unsigned int* gas1_t;
typedef __attribute__((address_space(3))) unsigned int* las3_t;
__device__ __forceinline__ void gll16(const ushort_t* g, ushort_t* l) {
  __builtin_amdgcn_global_load_lds((gas1_t)g, (las3_t)l, 16, 0, 0);
}

// ---------------- dtype detector ----------------
__global__ void detect_dtype(const void* Wn, int* flag) {
  if (blockIdx.x == 0 && threadIdx.x == 0) {
    const ushort_t* u = (const ushort_t*)Wn;
    int extreme = 0;
    for (int i = 0; i < 384; ++i) {
      float v = fabsf(bf2f(u[i]));
      if (v != 0.f && (v > 16.f || v < 6.1e-5f)) extreme++;
    }
    *flag = (extreme >= 20) ? 1 : 0;
  }
}

// ---------------- weight transpose-convert: dst[n*K+k] = src[(boff+k)*N + n] ----
__global__ void convert_wt(const void* __restrict__ src, ushort_t* __restrict__ dst,
                           int K, int N, int boff, const int* __restrict__ dflag) {
  int isf32 = *dflag;
  int tid = blockIdx.x * blockDim.x + threadIdx.x;
  if (tid >= N * K) return;
  int n = tid / K, k = tid % K;
  dst[tid] = f2bf(ldf(src, (size_t)(boff + k) * N + n, isf32));
}

// pack 6 attention vectors (3 layers x {a_src, a_dst}, 512 elems each) to bf16
__global__ void convert_att(const void* s1, const void* d1, const void* s2, const void* d2,
                            const void* s3, const void* d3, ushort_t* __restrict__ dst,
                            const int* __restrict__ dflag) {
  int isf32 = *dflag;
  int tid = blockIdx.x * blockDim.x + threadIdx.x;
  if (tid >= 6 * 512) return;
  int which = tid >> 9, idx = tid & 511;
  const void* p = which == 0 ? s1 : which == 1 ? d1 : which == 2 ? s2
                : which == 3 ? d2 : which == 4 ? s3 : d3;
  dst[tid] = f2bf(ldf(p, idx, isf32));
}

// ---------------- CSR build ----------------
__global__ void init_deg(int* deg, int* fill) {
  int n = blockIdx.x * blockDim.x + threadIdx.x;
  if (n < N_NODES) { deg[n] = 1; fill[n] = 0; }   // 1 = self loop
}

__global__ void count_edges(const int* __restrict__ ei, int* deg) {
  int e = blockIdx.x * blockDim.x + threadIdx.x;
  if (e < N_EDGES) atomicAdd(&deg[ei[N_EDGES + e]], 1);
}

__global__ void scan64(const int* __restrict__ deg, int* __restrict__ rowptr) {
  const int CHUNK = (N_NODES + 63) / 64;   // 782
  int t = threadIdx.x;
  int lo = t * CHUNK;
  int hi = lo + CHUNK; if (hi > N_NODES) hi = N_NODES;
  int s = 0;
  for (int i = lo; i < hi; ++i) s += deg[i];
  int inc = s;
  #pragma unroll
  for (int off = 1; off < 64; off <<= 1) {
    int u = __shfl_up(inc, off);
    if (t >= off) inc += u;
  }
  int run = inc - s;
  for (int i = lo; i < hi; ++i) { rowptr[i] = run; run += deg[i]; }
  if (t == 63) rowptr[N_NODES] = run;
}

__global__ void fill_csr(const int* __restrict__ ei, const int* __restrict__ rowptr,
                         int* fill, int* __restrict__ csr_src) {
  int e = blockIdx.x * blockDim.x + threadIdx.x;
  if (e >= EPRIME) return;
  int s, d;
  if (e < N_EDGES) { s = ei[e]; d = ei[N_EDGES + e]; }
  else             { s = d = e - N_EDGES; }
  int pos = rowptr[d] + atomicAdd(&fill[d], 1);
  csr_src[pos] = s;
}

// ---------------- node encoder ----------------
__global__ void encode_h(const void* __restrict__ x, const void* __restrict__ Wn,
                         const void* __restrict__ bn, ushort_t* __restrict__ h,
                         const int* __restrict__ dflag) {
  int isf32 = *dflag;
  int tid = blockIdx.x * blockDim.x + threadIdx.x;
  if (tid >= N_NODES * 64) return;
  int n = tid >> 6, j = tid & 63;
  float x0 = ldf(x, n * 3 + 0, isf32), x1 = ldf(x, n * 3 + 1, isf32), x2 = ldf(x, n * 3 + 2, isf32);
  float v = x0 * ldf(Wn, j, isf32) + x1 * ldf(Wn, 64 + j, isf32)
          + x2 * ldf(Wn, 128 + j, isf32) + ldf(bn, j, isf32);
  h[tid] = f2bf(v);
}

// ---------------- MFMA GEMM + fused attn-coef epilogue ------------------------
// C = A @ BT^T.  When att != nullptr (layer gemms, 128-col block = 2 heads,
// wave covers exactly one head = 2*by + wc), the epilogue computes
// asrc/adst[row,head] = dot(C_row_head, a_src/a_dst) via 16-lane reduce.
__global__ __launch_bounds__(256) void gemm_bt(
    const ushort_t* __restrict__ A, const ushort_t* __restrict__ BT,
    ushort_t* __restrict__ C, int K, int ldc,
    const ushort_t* __restrict__ att, float* __restrict__ asrc, float* __restrict__ adst)
{
  __shared__ __align__(16) ushort_t As[128][32];
  __shared__ __align__(16) ushort_t Bs[128][32];
  int tid = threadIdx.x;
  int wave = tid >> 6, lane = tid & 63;
  int wr = wave >> 1, wc = wave & 1;
  int row0 = blockIdx.x * 128, col0 = blockIdx.y * 128;
  int fm = lane & 15, fq = lane >> 4;

  f32x4_t acc[4][4];
  #pragma unroll
  for (int i = 0; i < 4; ++i)
    #pragma unroll
    for (int j = 0; j < 4; ++j) acc[i][j] = (f32x4_t){0.f, 0.f, 0.f, 0.f};

  int srow = wave * 32 + (lane >> 2);
  int skel = (lane & 3) * 8;
  const ushort_t* aG0 = A  + (size_t)(row0 + srow) * K + skel;
  const ushort_t* aG1 = A  + (size_t)(row0 + srow + 16) * K + skel;
  const ushort_t* bG0 = BT + (size_t)(col0 + srow) * K + skel;
  const ushort_t* bG1 = BT + (size_t)(col0 + srow + 16) * K + skel;
  ushort_t* aL0 = &As[wave * 32][0];
  ushort_t* aL1 = &As[wave * 32 + 16][0];
  ushort_t* bL0 = &Bs[wave * 32][0];
  ushort_t* bL1 = &Bs[wave * 32 + 16][0];

  for (int k0 = 0; k0 < K; k0 += 32) {
    gll16(aG0 + k0, aL0);
    gll16(aG1 + k0, aL1);
    gll16(bG0 + k0, bL0);
    gll16(bG1 + k0, bL1);
    __syncthreads();
    bf16x8_t af[4], bfr[4];
    #pragma unroll
    for (int i = 0; i < 4; ++i) af[i]  = *(const bf16x8_t*)&As[64 * wr + 16 * i + fm][fq * 8];
    #pragma unroll
    for (int j = 0; j < 4; ++j) bfr[j] = *(const bf16x8_t*)&Bs[64 * wc + 16 * j + fm][fq * 8];
    #pragma unroll
    for (int i = 0; i < 4; ++i)
      #pragma unroll
      for (int j = 0; j < 4; ++j)
        acc[i][j] = __builtin_amdgcn_mfma_f32_16x16x32_bf16(af[i], bfr[j], acc[i][j], 0, 0, 0);
    __syncthreads();
  }

  int do_att = (att != nullptr);
  int head = 2 * blockIdx.y + wc;
  float sa[4], sd[4];
  if (do_att) {
    #pragma unroll
    for (int j = 0; j < 4; ++j) {
      int ch = 16 * j + fm;
      sa[j] = bf2f(att[head * CH + ch]);
      sd[j] = bf2f(att[512 + head * CH + ch]);
    }
  }

  // C/D layout: col = lane&15, row = (lane>>4)*4 + reg
  #pragma unroll
  for (int i = 0; i < 4; ++i) {
    int rowb = row0 + 64 * wr + 16 * i + fq * 4;
    #pragma unroll
    for (int r = 0; r < 4; ++r) {
      int row = rowb + r;
      float ss = 0.f, dd = 0.f;
      #pragma unroll
      for (int j = 0; j < 4; ++j) {
        ushort_t uv = f2bf(acc[i][j][r]);
        C[(size_t)row * ldc + col0 + 64 * wc + 16 * j + fm] = uv;
        if (do_att) {
          float cv = bf2f(uv);
          ss += cv * sa[j];
          dd += cv * sd[j];
        }
      }
      if (do_att) {
        #pragma unroll
        for (int off = 8; off > 0; off >>= 1) {
          ss += __shfl_down(ss, off);
          dd += __shfl_down(dd, off);
        }
        if (fm == 0 && row < N_NODES) {
          asrc[row * HEADS + head] = ss;
          adst[row * HEADS + head] = dd;
        }
      }
    }
  }
}

// ---------------- maxless-softmax aggregation (gather per dst), unroll x8 -----
// thread t -> channels (2t, 2t+1), head t>>5.
// mean_mode=0: out[n,512] = bf16(elu(acc + bc) + (x@Wr + br)[n])
// mean_mode=1: out[n,64]  = bf16(elu(mean_h(acc) + bc)); fused node head -> outh
// sumv stores the RECIPROCAL 1/l (consumed only by edge_head as a multiply).
__global__ __launch_bounds__(256) void aggregate(
    const int* __restrict__ rowptr, const int* __restrict__ csr_src,
    const float* __restrict__ asrc, const float* __restrict__ adst,
    float* __restrict__ sumv,
    const ushort_t* __restrict__ g,
    const void* __restrict__ x, const void* __restrict__ Wr,
    const void* __restrict__ br, const void* __restrict__ bc,
    ushort_t* __restrict__ out, int mean_mode,
    const void* __restrict__ Wo, const void* __restrict__ bo,
    void* __restrict__ outh, const int* __restrict__ dflag)
{
  int isf32 = *dflag;
  __shared__ float sx[3];
  int n = blockIdx.x;
  int t = threadIdx.x;
  if (t < 3) sx[t] = ldf(x, n * 3 + t, isf32);
  __syncthreads();

  int start = rowptr[n], end = rowptr[n + 1];
  int c0 = t * 2;
  int h  = t >> 5;
  int i0 = n * HEADS + h;
  float ad = adst[i0];

  float l = 0.f, a0 = 0.f, a1 = 0.f;
  int i = start;
  for (; i + 8 <= end; i += 8) {
    int s[8];
    #pragma unroll
    for (int k = 0; k < 8; ++k) s[k] = csr_src[i + k];
    float e[8];
    unsigned int gv[8];
    #pragma unroll
    for (int k = 0; k < 8; ++k) {
      e[k]  = asrc[s[k] * HEADS + h] + ad;
      gv[k] = *(const unsigned int*)(g + (size_t)s[k] * FDIM + c0);
    }
    #pragma unroll
    for (int k = 0; k < 8; ++k) {
      float p = __expf(leakyf(e[k]));
      l  += p;
      a0 += p * bf2f((ushort_t)(gv[k] & 0xffffu));
      a1 += p * bf2f((ushort_t)(gv[k] >> 16));
    }
  }
  for (; i + 2 <= end; i += 2) {
    int s0 = csr_src[i], s1 = csr_src[i + 1];
    float e0 = asrc[s0 * HEADS + h] + ad;
    float e1 = asrc[s1 * HEADS + h] + ad;
    unsigned int g0 = *(const unsigned int*)(g + (size_t)s0 * FDIM + c0);
    unsigned int g1 = *(const unsigned int*)(g + (size_t)s1 * FDIM + c0);
    float p0 = __expf(leakyf(e0)), p1 = __expf(leakyf(e1));
    l  += p0 + p1;
    a0 += p0 * bf2f((ushort_t)(g0 & 0xffffu)) + p1 * bf2f((ushort_t)(g1 & 0xffffu));
    a1 += p0 * bf2f((ushort_t)(g0 >> 16))     + p1 * bf2f((ushort_t)(g1 >> 16));
  }
  if (i < end) {
    int s0 = csr_src[i];
    float p0 = __expf(leakyf(asrc[s0 * HEADS + h] + ad));
    unsigned int g0 = *(const unsigned int*)(g + (size_t)s0 * FDIM + c0);
    l  += p0;
    a0 += p0 * bf2f((ushort_t)(g0 & 0xffffu));
    a1 += p0 * bf2f((ushort_t)(g0 >> 16));
  }
  a0 /= l;
  a1 /= l;
  if ((t & 31) == 0) sumv[i0] = 1.f / l;   // reciprocal; one writer per (node,head)

  if (!mean_mode) {
    float r0 = sx[0] * ldf(Wr, c0, isf32)         + sx[1] * ldf(Wr, 512 + c0, isf32)
             + sx[2] * ldf(Wr, 1024 + c0, isf32)  + ldf(br, c0, isf32);
    float r1 = sx[0] * ldf(Wr, c0 + 1, isf32)     + sx[1] * ldf(Wr, 512 + c0 + 1, isf32)
             + sx[2] * ldf(Wr, 1024 + c0 + 1, isf32) + ldf(br, c0 + 1, isf32);
    unsigned int o0 = f2bf(eluf(a0 + ldf(bc, c0, isf32)) + r0);
    unsigned int o1 = f2bf(eluf(a1 + ldf(bc, c0 + 1, isf32)) + r1);
    *(unsigned int*)(out + (size_t)n * FDIM + c0) = o0 | (o1 << 16);
  } else {
    __shared__ float red[512];
    red[c0] = a0; red[c0 + 1] = a1;
    __syncthreads();
    if (t < 64) {                               // wave 0, uniform branch
      float tot = 0.f;
      #pragma unroll
      for (int hh = 0; hh < 8; ++hh) tot += red[t + 64 * hh];
      ushort_t uv = f2bf(eluf(tot * 0.125f + ldf(bc, t, isf32)));
      out[(size_t)n * CH + t] = uv;
      // fused node head on the bf16-rounded ne value (matches old node_head)
      float nv = bf2f(uv);
      float p0 = nv * ldf(Wo, t * 2 + 0, isf32);
      float p1 = nv * ldf(Wo, t * 2 + 1, isf32);
      float vv = (t & 1) ? p1 : p0;
      float ww = (t & 1) ? p0 : p1;
      vv += __shfl_xor(ww, 1);
      #pragma unroll
      for (int off = 2; off < 64; off <<= 1) vv += __shfl_xor(vv, off);
      if (t < 2) stf(outh, (size_t)n * 2 + t, vv + ldf(bo, t, isf32), isf32);
    }
  }
}

// ---------------- edge head v6: v3 structure, DS-free inner loop --------------
// Original edge order (contiguous stores), 2-edge pipeline, fixed 16 iters.
// Changes vs v3: (a) index loads scalarized via readfirstlane -> s_load, gather
// address math on SALU; (b) alpha broadcast via v_readlane into SGPRs (no
// ds_bpermute, inner FMAs use SGPR operand); (c) final 64-lane reduce via DPP
// butterfly (pure VALU, result in lane 63); (d) precomputed 1/sum (no division).
#define EPW 32
__global__ __launch_bounds__(256) void edge_head6(
    const int* __restrict__ ei, const float* __restrict__ asrc, const float* __restrict__ adst,
    const float* __restrict__ rsumv,
    const ushort_t* __restrict__ pq, const void* __restrict__ Wm1,
    const void* __restrict__ bm1, const void* __restrict__ Wm2,
    const void* __restrict__ bm2, void* __restrict__ out,
    const int* __restrict__ dflag)
{
  int isf32 = *dflag;
  int lane = threadIdx.x & 63;
  int c0 = lane * 4;
  int h = lane & 7;
  float w1r[8][4], w2a[4], w2b[4], b1r[4];
  #pragma unroll
  for (int hh = 0; hh < 8; ++hh)
    #pragma unroll
    for (int j = 0; j < 4; ++j)
      w1r[hh][j] = ldf(Wm1, (64 + hh) * 256 + c0 + j, isf32);
  #pragma unroll
  for (int j = 0; j < 4; ++j) {
    w2a[j] = ldf(Wm2, (c0 + j) * 2 + 0, isf32);
    w2b[j] = ldf(Wm2, (c0 + j) * 2 + 1, isf32);
    b1r[j] = ldf(bm1, c0 + j, isf32);
  }
  float bo0 = ldf(bm2, 0, isf32), bo1 = ldf(bm2, 1, isf32);

  int wid = blockIdx.x * 4 + (threadIdx.x >> 6);
  int e0 = wid * EPW;                       // EPW*4=128 divides N_EDGES exactly
  for (int e = e0; e < e0 + EPW; e += 2) {
    int eu = __builtin_amdgcn_readfirstlane(e);     // uniform -> s_load of indices
    int sA = ei[eu],     dA = ei[N_EDGES + eu];
    int sB = ei[eu + 1], dB = ei[N_EDGES + eu + 1];
    float vA = asrc[sA * HEADS + h] + adst[dA * HEADS + h];
    float vB = asrc[sB * HEADS + h] + adst[dB * HEADS + h];
    float rsA = rsumv[dA * HEADS + h], rsB = rsumv[dB * HEADS + h];
    ushort4 pvA = *(const ushort4*)(pq + (size_t)sA * FDIM + c0);
    ushort4 qvA = *(const ushort4*)(pq + (size_t)dA * FDIM + 256 + c0);
    ushort4 pvB = *(const ushort4*)(pq + (size_t)sB * FDIM + c0);
    ushort4 qvB = *(const ushort4*)(pq + (size_t)dB * FDIM + 256 + c0);
    float aA = __expf(leakyf(vA)) * rsA;
    float aB = __expf(leakyf(vB)) * rsB;
    // alpha lives in lanes 0..7 (lane&7 == head); lift to SGPRs via readlane
    float alA[8], alB[8];
    #pragma unroll
    for (int hh = 0; hh < 8; ++hh) {
      alA[hh] = __int_as_float(__builtin_amdgcn_readlane(__float_as_int(aA), hh));
      alB[hh] = __int_as_float(__builtin_amdgcn_readlane(__float_as_int(aB), hh));
    }

    float accA0 = 0.f, accA1 = 0.f, accB0 = 0.f, accB1 = 0.f;
    float pA[4] = { bf2f(pvA.x), bf2f(pvA.y), bf2f(pvA.z), bf2f(pvA.w) };
    float qA[4] = { bf2f(qvA.x), bf2f(qvA.y), bf2f(qvA.z), bf2f(qvA.w) };
    float pB[4] = { bf2f(pvB.x), bf2f(pvB.y), bf2f(pvB.z), bf2f(pvB.w) };
    float qB[4] = { bf2f(qvB.x), bf2f(qvB.y), bf2f(qvB.z), bf2f(qvB.w) };
    #pragma unroll
    for (int j = 0; j < 4; ++j) {
      float hvA = pA[j] + qA[j] + b1r[j];
      float hvB = pB[j] + qB[j] + b1r[j];
      #pragma unroll
      for (int hh = 0; hh < 8; ++hh) {
        hvA += alA[hh] * w1r[hh][j];
        hvB += alB[hh] * w1r[hh][j];
      }
      hvA = fmaxf(hvA, 0.f);
      hvB = fmaxf(hvB, 0.f);
      accA0 += hvA * w2a[j]; accA1 += hvA * w2b[j];
      accB0 += hvB * w2a[j]; accB1 += hvB * w2b[j];
    }
    accA0 = dpp_sum64(accA0);
    accA1 = dpp_sum64(accA1);
    accB0 = dpp_sum64(accB0);
    accB1 = dpp_sum64(accB1);
    if (lane == 63) {
      stf(out, 100000 + (size_t)e * 2 + 0, accA0 + bo0, isf32);
      stf(out, 100000 + (size_t)e * 2 + 1, accA1 + bo1, isf32);
      stf(out, 100000 + (size_t)e * 2 + 2, accB0 + bo0, isf32);
      stf(out, 100000 + (size_t)e * 2 + 3, accB1 + bo1, isf32);
    }
  }
}

// ---------------- launch ----------------
extern "C" void kernel_launch(void* const* d_in, const int* in_sizes, int n_in,
                              void* d_out, int out_size, void* d_ws, size_t ws_size,
                              hipStream_t stream) {
  const void* x   = d_in[0];
  const int*  ei  = (const int*)d_in[1];
  const void* Wn  = d_in[4];
  const void* bn  = d_in[5];
  const void* Wr  = d_in[6];
  const void* br  = d_in[7];
  const void* W1  = d_in[8];
  const void* as1 = d_in[9];
  const void* ad1 = d_in[10];
  const void* bc1 = d_in[11];
  const void* W2  = d_in[12];
  const void* as2 = d_in[13];
  const void* ad2 = d_in[14];
  const void* bc2 = d_in[15];
  const void* W3  = d_in[16];
  const void* as3 = d_in[17];
  const void* ad3 = d_in[18];
  const void* bc3 = d_in[19];
  const void* Wo  = d_in[20];
  const void* bo  = d_in[21];
  const void* Wm1 = d_in[22];
  const void* bm1 = d_in[23];
  const void* Wm2 = d_in[24];
  const void* bm2 = d_in[25];

  char* ws = (char*)d_ws;
  size_t off = 0;
  auto take = [&](size_t bytes) -> char* {
    char* p = ws + off;
    off += (bytes + 255) & ~(size_t)255;
    return p;
  };
  ushort_t* h_bf   = (ushort_t*)take((size_t)NPAD * 64 * 2);       // enc out / node_embedding
  ushort_t* g_bf   = (ushort_t*)take((size_t)NPAD * FDIM * 2);     // gemm out / P|Q
  ushort_t* o_bf   = (ushort_t*)take((size_t)NPAD * FDIM * 2);     // layer out
  float*    asrc   = (float*)take((size_t)N_NODES * HEADS * 4);
  float*    adst   = (float*)take((size_t)N_NODES * HEADS * 4);
  float*    sumv   = (float*)take((size_t)N_NODES * HEADS * 4);
  int*      rowptr = (int*)take((size_t)(N_NODES + 1) * 4);
  int*      csr_src= (int*)take((size_t)EPRIME * 4);
  int*      deg    = (int*)take((size_t)N_NODES * 4);
  int*      fillc  = (int*)take((size_t)N_NODES * 4);
  int*      dflag  = (int*)take(256);
  ushort_t* WT1    = (ushort_t*)take((size_t)512 * 64 * 2);        // W1^T  [512][64]
  ushort_t* WT2    = (ushort_t*)take((size_t)512 * 512 * 2);       // W2^T  [512][512]
  ushort_t* WT3    = (ushort_t*)take((size_t)512 * 512 * 2);       // W3^T  [512][512]
  ushort_t* WTPQ   = (ushort_t*)take((size_t)512 * 64 * 2);        // [P^T ; Q^T] combined
  ushort_t* attv   = (ushort_t*)take((size_t)6 * 512 * 2);         // packed a_src/a_dst x3

  dim3 b256(256);
  const int MB = NPAD / 128;  // 391

  detect_dtype<<<dim3(1), dim3(64), 0, stream>>>(Wn, dflag);

  // weight conversion (transpose to [n][k], bf16); W1 is [64,512] -> K=64
  convert_wt<<<dim3(128),  b256, 0, stream>>>(W1, WT1, 64, 512, 0, dflag);
  convert_wt<<<dim3(1024), b256, 0, stream>>>(W2, WT2, 512, 512, 0, dflag);
  convert_wt<<<dim3(1024), b256, 0, stream>>>(W3, WT3, 512, 512, 0, dflag);
  convert_wt<<<dim3(64),   b256, 0, stream>>>(Wm1, WTPQ,            64, 256, 0,  dflag);
  convert_wt<<<dim3(64),   b256, 0, stream>>>(Wm1, WTPQ + 256 * 64, 64, 256, 72, dflag);
  convert_att<<<dim3(12),  b256, 0, stream>>>(as1, ad1, as2, ad2, as3, ad3, attv, dflag);

  // CSR build
  init_deg<<<dim3((N_NODES + 255) / 256), b256, 0, stream>>>(deg, fillc);
  count_edges<<<dim3((N_EDGES + 255) / 256), b256, 0, stream>>>(ei, deg);
  scan64<<<dim3(1), dim3(64), 0, stream>>>(deg, rowptr);
  fill_csr<<<dim3((EPRIME + 255) / 256), b256, 0, stream>>>(ei, rowptr, fillc, csr_src);

  // node encoder
  encode_h<<<dim3((N_NODES * 64 + 255) / 256), b256, 0, stream>>>(x, Wn, bn, h_bf, dflag);

  // ---- GAT layer 1 (in: h_bf [NPAD,64]); attn fused in gemm epilogue ----
  gemm_bt<<<dim3(MB, 4), b256, 0, stream>>>(h_bf, WT1, g_bf, 64, 512,
                                            attv, asrc, adst);
  aggregate<<<dim3(N_NODES), b256, 0, stream>>>(rowptr, csr_src, asrc, adst, sumv,
                                                g_bf, x, Wr, br, bc1, o_bf, 0,
                                                nullptr, nullptr, d_out, dflag);

  // ---- GAT layer 2 ----
  gemm_bt<<<dim3(MB, 4), b256, 0, stream>>>(o_bf, WT2, g_bf, 512, 512,
                                            attv + 1024, asrc, adst);
  aggregate<<<dim3(N_NODES), b256, 0, stream>>>(rowptr, csr_src, asrc, adst, sumv,
                                                g_bf, x, Wr, br, bc2, o_bf, 0,
                                                nullptr, nullptr, d_out, dflag);

  // ---- GAT layer 3 (mean over heads -> ne in h_bf; node head fused) ----
  gemm_bt<<<dim3(MB, 4), b256, 0, stream>>>(o_bf, WT3, g_bf, 512, 512,
                                            attv + 2048, asrc, adst);
  aggregate<<<dim3(N_NODES), b256, 0, stream>>>(rowptr, csr_src, asrc, adst, sumv,
                                                g_bf, x, Wr, br, bc3, h_bf, 1,
                                                Wo, bo, d_out, dflag);

  // ---- edge head: P|Q in one gemm, then per-edge MLP (DS-free) ----
  gemm_bt<<<dim3(MB, 4), b256, 0, stream>>>(h_bf, WTPQ, g_bf, 64, 512,
                                            nullptr, nullptr, nullptr);
  edge_head6<<<dim3(N_EDGES / (EPW * 4)), b256, 0, stream>>>(ei, asrc, adst, sumv, g_bf,
                                                             Wm1, bm1, Wm2, bm2,
                                                             d_out, dflag);
}

// Round 4
// 1074.946 us; speedup vs baseline: 1.2276x; 1.1162x over previous
//
#include <hip/hip_runtime.h>
#include <hip/hip_bf16.h>
#include <math.h>

#define N_NODES 50000
#define NPAD    50048                  // N_NODES rounded up to 128 (gemm tiles, no guards)
#define N_EDGES 800000
#define EPRIME  (N_EDGES + N_NODES)   // edges + self loops
#define HEADS 8
#define CH 64
#define FDIM 512                       // HEADS*CH

typedef unsigned short ushort_t;
typedef __attribute__((ext_vector_type(8))) short bf16x8_t;  // 8 bf16 = 4 VGPRs
typedef __attribute__((ext_vector_type(4))) float f32x4_t;

__device__ __forceinline__ float bf2f(unsigned short u) {
  union { unsigned int i; float f; } v; v.i = ((unsigned int)u) << 16; return v.f;
}
__device__ __forceinline__ unsigned short f2bf(float f) {
  union { float f; unsigned int i; } v; v.f = f;
  unsigned int x = v.i;
  return (unsigned short)((x + 0x7fffu + ((x >> 16) & 1u)) >> 16);  // RNE
}
__device__ __forceinline__ float ldf(const void* p, size_t idx, int isf32) {
  return isf32 ? ((const float*)p)[idx] : bf2f(((const ushort_t*)p)[idx]);
}
__device__ __forceinline__ void stf(void* p, size_t idx, float v, int isf32) {
  if (isf32) ((float*)p)[idx] = v;
  else       ((ushort_t*)p)[idx] = f2bf(v);
}
__device__ __forceinline__ float leakyf(float v) { return v >= 0.f ? v : 0.2f * v; }
__device__ __forceinline__ float eluf(float v)   { return v > 0.f ? v : expm1f(v); }

// wave64 sum via DPP butterfly (LLVM AtomicOptimizer sequence); full sum valid
// in lanes 48..63 (use lane 63). Pure VALU — no DS pipe, no LDS.
__device__ __forceinline__ float dpp_sum64(float x) {
  x += __int_as_float(__builtin_amdgcn_update_dpp(0, __float_as_int(x), 0xB1, 0xf, 0xf, false)); // quad_perm [1,0,3,2]
  x += __int_as_float(__builtin_amdgcn_update_dpp(0, __float_as_int(x), 0x4E, 0xf, 0xf, false)); // quad_perm [2,3,0,1]
  x += __int_as_float(__builtin_amdgcn_update_dpp(0, __float_as_int(x), 0x141, 0xf, 0xf, false)); // row_half_mirror
  x += __int_as_float(__builtin_amdgcn_update_dpp(0, __float_as_int(x), 0x140, 0xf, 0xf, false)); // row_mirror
  x += __int_as_float(__builtin_amdgcn_update_dpp(0, __float_as_int(x), 0x142, 0xa, 0xf, false)); // row_bcast:15 rows 1,3
  x += __int_as_float(__builtin_amdgcn_update_dpp(0, __float_as_int(x), 0x143, 0xc, 0xf, false)); // row_bcast:31 rows 2,3
  return x;
}

// async global->LDS, 16B per lane; LDS dest = wave-uniform base + lane*16
typedef const __attribute__((address_space(1))) unsigned int* gas1_t;
typedef __attribute__((address_space(3))) unsigned int* las3_t;
__device__ __forceinline__ void gll16(const ushort_t* g, ushort_t* l) {
  __builtin_amdgcn_global_load_lds((gas1_t)g, (las3_t)l, 16, 0, 0);
}

// ---------------- dtype detector ----------------
__global__ void detect_dtype(const void* Wn, int* flag) {
  if (blockIdx.x == 0 && threadIdx.x == 0) {
    const ushort_t* u = (const ushort_t*)Wn;
    int extreme = 0;
    for (int i = 0; i < 384; ++i) {
      float v = fabsf(bf2f(u[i]));
      if (v != 0.f && (v > 16.f || v < 6.1e-5f)) extreme++;
    }
    *flag = (extreme >= 20) ? 1 : 0;
  }
}

// ---------------- weight transpose-convert: dst[n*K+k] = src[(boff+k)*N + n] ----
__global__ void convert_wt(const void* __restrict__ src, ushort_t* __restrict__ dst,
                           int K, int N, int boff, const int* __restrict__ dflag) {
  int isf32 = *dflag;
  int tid = blockIdx.x * blockDim.x + threadIdx.x;
  if (tid >= N * K) return;
  int n = tid / K, k = tid % K;
  dst[tid] = f2bf(ldf(src, (size_t)(boff + k) * N + n, isf32));
}

// pack 6 attention vectors (3 layers x {a_src, a_dst}, 512 elems each) to bf16
__global__ void convert_att(const void* s1, const void* d1, const void* s2, const void* d2,
                            const void* s3, const void* d3, ushort_t* __restrict__ dst,
                            const int* __restrict__ dflag) {
  int isf32 = *dflag;
  int tid = blockIdx.x * blockDim.x + threadIdx.x;
  if (tid >= 6 * 512) return;
  int which = tid >> 9, idx = tid & 511;
  const void* p = which == 0 ? s1 : which == 1 ? d1 : which == 2 ? s2
                : which == 3 ? d2 : which == 4 ? s3 : d3;
  dst[tid] = f2bf(ldf(p, idx, isf32));
}

// ---------------- CSR build ----------------
__global__ void init_deg(int* deg, int* fill) {
  int n = blockIdx.x * blockDim.x + threadIdx.x;
  if (n < N_NODES) { deg[n] = 1; fill[n] = 0; }   // 1 = self loop
}

__global__ void count_edges(const int* __restrict__ ei, int* deg) {
  int e = blockIdx.x * blockDim.x + threadIdx.x;
  if (e < N_EDGES) atomicAdd(&deg[ei[N_EDGES + e]], 1);
}

// parallel exclusive scan of deg[0..N_NODES) -> rowptr; 1 block x 1024 threads.
// 16 waves hide the L2 latency the old 1-wave scan64 serialized on (200us -> ~12us).
__global__ __launch_bounds__(1024) void scan1024(const int* __restrict__ deg,
                                                 int* __restrict__ rowptr) {
  const int CHUNK = (N_NODES + 1023) / 1024;   // 49
  int t = threadIdx.x;
  int wave = t >> 6, lane = t & 63;
  int lo = t * CHUNK;
  int hi = lo + CHUNK; if (hi > N_NODES) hi = N_NODES;
  int s = 0;
  for (int i = lo; i < hi; ++i) s += deg[i];
  int inc = s;
  #pragma unroll
  for (int off = 1; off < 64; off <<= 1) {
    int u = __shfl_up(inc, off);
    if (lane >= off) inc += u;
  }
  __shared__ int wsum[16];
  if (lane == 63) wsum[wave] = inc;
  __syncthreads();
  int wbase = 0;
  for (int w = 0; w < wave; ++w) wbase += wsum[w];
  int run = wbase + inc - s;                   // exclusive prefix for this thread
  for (int i = lo; i < hi; ++i) { rowptr[i] = run; run += deg[i]; }
  if (t == 1023) rowptr[N_NODES] = run;
}

__global__ void fill_csr(const int* __restrict__ ei, const int* __restrict__ rowptr,
                         int* fill, int* __restrict__ csr_src) {
  int e = blockIdx.x * blockDim.x + threadIdx.x;
  if (e >= EPRIME) return;
  int s, d;
  if (e < N_EDGES) { s = ei[e]; d = ei[N_EDGES + e]; }
  else             { s = d = e - N_EDGES; }
  int pos = rowptr[d] + atomicAdd(&fill[d], 1);
  csr_src[pos] = s;
}

// ---------------- node encoder ----------------
__global__ void encode_h(const void* __restrict__ x, const void* __restrict__ Wn,
                         const void* __restrict__ bn, ushort_t* __restrict__ h,
                         const int* __restrict__ dflag) {
  int isf32 = *dflag;
  int tid = blockIdx.x * blockDim.x + threadIdx.x;
  if (tid >= N_NODES * 64) return;
  int n = tid >> 6, j = tid & 63;
  float x0 = ldf(x, n * 3 + 0, isf32), x1 = ldf(x, n * 3 + 1, isf32), x2 = ldf(x, n * 3 + 2, isf32);
  float v = x0 * ldf(Wn, j, isf32) + x1 * ldf(Wn, 64 + j, isf32)
          + x2 * ldf(Wn, 128 + j, isf32) + ldf(bn, j, isf32);
  h[tid] = f2bf(v);
}

// ---------------- MFMA GEMM + fused attn-coef epilogue ------------------------
// C = A @ BT^T.  When att != nullptr (layer gemms, 128-col block = 2 heads,
// wave covers exactly one head = 2*by + wc), the epilogue computes
// asrc/adst[row,head] = dot(C_row_head, a_src/a_dst) via 16-lane reduce.
__global__ __launch_bounds__(256) void gemm_bt(
    const ushort_t* __restrict__ A, const ushort_t* __restrict__ BT,
    ushort_t* __restrict__ C, int K, int ldc,
    const ushort_t* __restrict__ att, float* __restrict__ asrc, float* __restrict__ adst)
{
  __shared__ __align__(16) ushort_t As[128][32];
  __shared__ __align__(16) ushort_t Bs[128][32];
  int tid = threadIdx.x;
  int wave = tid >> 6, lane = tid & 63;
  int wr = wave >> 1, wc = wave & 1;
  int row0 = blockIdx.x * 128, col0 = blockIdx.y * 128;
  int fm = lane & 15, fq = lane >> 4;

  f32x4_t acc[4][4];
  #pragma unroll
  for (int i = 0; i < 4; ++i)
    #pragma unroll
    for (int j = 0; j < 4; ++j) acc[i][j] = (f32x4_t){0.f, 0.f, 0.f, 0.f};

  int srow = wave * 32 + (lane >> 2);
  int skel = (lane & 3) * 8;
  const ushort_t* aG0 = A  + (size_t)(row0 + srow) * K + skel;
  const ushort_t* aG1 = A  + (size_t)(row0 + srow + 16) * K + skel;
  const ushort_t* bG0 = BT + (size_t)(col0 + srow) * K + skel;
  const ushort_t* bG1 = BT + (size_t)(col0 + srow + 16) * K + skel;
  ushort_t* aL0 = &As[wave * 32][0];
  ushort_t* aL1 = &As[wave * 32 + 16][0];
  ushort_t* bL0 = &Bs[wave * 32][0];
  ushort_t* bL1 = &Bs[wave * 32 + 16][0];

  for (int k0 = 0; k0 < K; k0 += 32) {
    gll16(aG0 + k0, aL0);
    gll16(aG1 + k0, aL1);
    gll16(bG0 + k0, bL0);
    gll16(bG1 + k0, bL1);
    __syncthreads();
    bf16x8_t af[4], bfr[4];
    #pragma unroll
    for (int i = 0; i < 4; ++i) af[i]  = *(const bf16x8_t*)&As[64 * wr + 16 * i + fm][fq * 8];
    #pragma unroll
    for (int j = 0; j < 4; ++j) bfr[j] = *(const bf16x8_t*)&Bs[64 * wc + 16 * j + fm][fq * 8];
    #pragma unroll
    for (int i = 0; i < 4; ++i)
      #pragma unroll
      for (int j = 0; j < 4; ++j)
        acc[i][j] = __builtin_amdgcn_mfma_f32_16x16x32_bf16(af[i], bfr[j], acc[i][j], 0, 0, 0);
    __syncthreads();
  }

  int do_att = (att != nullptr);
  int head = 2 * blockIdx.y + wc;
  float sa[4], sd[4];
  if (do_att) {
    #pragma unroll
    for (int j = 0; j < 4; ++j) {
      int ch = 16 * j + fm;
      sa[j] = bf2f(att[head * CH + ch]);
      sd[j] = bf2f(att[512 + head * CH + ch]);
    }
  }

  // C/D layout: col = lane&15, row = (lane>>4)*4 + reg
  #pragma unroll
  for (int i = 0; i < 4; ++i) {
    int rowb = row0 + 64 * wr + 16 * i + fq * 4;
    #pragma unroll
    for (int r = 0; r < 4; ++r) {
      int row = rowb + r;
      float ss = 0.f, dd = 0.f;
      #pragma unroll
      for (int j = 0; j < 4; ++j) {
        ushort_t uv = f2bf(acc[i][j][r]);
        C[(size_t)row * ldc + col0 + 64 * wc + 16 * j + fm] = uv;
        if (do_att) {
          float cv = bf2f(uv);
          ss += cv * sa[j];
          dd += cv * sd[j];
        }
      }
      if (do_att) {
        #pragma unroll
        for (int off = 8; off > 0; off >>= 1) {
          ss += __shfl_down(ss, off);
          dd += __shfl_down(dd, off);
        }
        if (fm == 0 && row < N_NODES) {
          asrc[row * HEADS + head] = ss;
          adst[row * HEADS + head] = dd;
        }
      }
    }
  }
}

// ---------------- maxless-softmax aggregation (gather per dst), unroll x8 -----
// thread t -> channels (2t, 2t+1), head t>>5.
// mean_mode=0: out[n,512] = bf16(elu(acc + bc) + (x@Wr + br)[n])
// mean_mode=1: out[n,64]  = bf16(elu(mean_h(acc) + bc)); fused node head -> outh
// sumv stores the RECIPROCAL 1/l (consumed only by edge_head as a multiply).
__global__ __launch_bounds__(256) void aggregate(
    const int* __restrict__ rowptr, const int* __restrict__ csr_src,
    const float* __restrict__ asrc, const float* __restrict__ adst,
    float* __restrict__ sumv,
    const ushort_t* __restrict__ g,
    const void* __restrict__ x, const void* __restrict__ Wr,
    const void* __restrict__ br, const void* __restrict__ bc,
    ushort_t* __restrict__ out, int mean_mode,
    const void* __restrict__ Wo, const void* __restrict__ bo,
    void* __restrict__ outh, const int* __restrict__ dflag)
{
  int isf32 = *dflag;
  __shared__ float sx[3];
  int n = blockIdx.x;
  int t = threadIdx.x;
  if (t < 3) sx[t] = ldf(x, n * 3 + t, isf32);
  __syncthreads();

  int start = rowptr[n], end = rowptr[n + 1];
  int c0 = t * 2;
  int h  = t >> 5;
  int i0 = n * HEADS + h;
  float ad = adst[i0];

  float l = 0.f, a0 = 0.f, a1 = 0.f;
  int i = start;
  for (; i + 8 <= end; i += 8) {
    int s[8];
    #pragma unroll
    for (int k = 0; k < 8; ++k) s[k] = csr_src[i + k];
    float e[8];
    unsigned int gv[8];
    #pragma unroll
    for (int k = 0; k < 8; ++k) {
      e[k]  = asrc[s[k] * HEADS + h] + ad;
      gv[k] = *(const unsigned int*)(g + (size_t)s[k] * FDIM + c0);
    }
    #pragma unroll
    for (int k = 0; k < 8; ++k) {
      float p = __expf(leakyf(e[k]));
      l  += p;
      a0 += p * bf2f((ushort_t)(gv[k] & 0xffffu));
      a1 += p * bf2f((ushort_t)(gv[k] >> 16));
    }
  }
  for (; i + 2 <= end; i += 2) {
    int s0 = csr_src[i], s1 = csr_src[i + 1];
    float e0 = asrc[s0 * HEADS + h] + ad;
    float e1 = asrc[s1 * HEADS + h] + ad;
    unsigned int g0 = *(const unsigned int*)(g + (size_t)s0 * FDIM + c0);
    unsigned int g1 = *(const unsigned int*)(g + (size_t)s1 * FDIM + c0);
    float p0 = __expf(leakyf(e0)), p1 = __expf(leakyf(e1));
    l  += p0 + p1;
    a0 += p0 * bf2f((ushort_t)(g0 & 0xffffu)) + p1 * bf2f((ushort_t)(g1 & 0xffffu));
    a1 += p0 * bf2f((ushort_t)(g0 >> 16))     + p1 * bf2f((ushort_t)(g1 >> 16));
  }
  if (i < end) {
    int s0 = csr_src[i];
    float p0 = __expf(leakyf(asrc[s0 * HEADS + h] + ad));
    unsigned int g0 = *(const unsigned int*)(g + (size_t)s0 * FDIM + c0);
    l  += p0;
    a0 += p0 * bf2f((ushort_t)(g0 & 0xffffu));
    a1 += p0 * bf2f((ushort_t)(g0 >> 16));
  }
  a0 /= l;
  a1 /= l;
  if ((t & 31) == 0) sumv[i0] = 1.f / l;   // reciprocal; one writer per (node,head)

  if (!mean_mode) {
    float r0 = sx[0] * ldf(Wr, c0, isf32)         + sx[1] * ldf(Wr, 512 + c0, isf32)
             + sx[2] * ldf(Wr, 1024 + c0, isf32)  + ldf(br, c0, isf32);
    float r1 = sx[0] * ldf(Wr, c0 + 1, isf32)     + sx[1] * ldf(Wr, 512 + c0 + 1, isf32)
             + sx[2] * ldf(Wr, 1024 + c0 + 1, isf32) + ldf(br, c0 + 1, isf32);
    unsigned int o0 = f2bf(eluf(a0 + ldf(bc, c0, isf32)) + r0);
    unsigned int o1 = f2bf(eluf(a1 + ldf(bc, c0 + 1, isf32)) + r1);
    *(unsigned int*)(out + (size_t)n * FDIM + c0) = o0 | (o1 << 16);
  } else {
    __shared__ float red[512];
    red[c0] = a0; red[c0 + 1] = a1;
    __syncthreads();
    if (t < 64) {                               // wave 0, uniform branch
      float tot = 0.f;
      #pragma unroll
      for (int hh = 0; hh < 8; ++hh) tot += red[t + 64 * hh];
      ushort_t uv = f2bf(eluf(tot * 0.125f + ldf(bc, t, isf32)));
      out[(size_t)n * CH + t] = uv;
      // fused node head on the bf16-rounded ne value (matches old node_head)
      float nv = bf2f(uv);
      float p0 = nv * ldf(Wo, t * 2 + 0, isf32);
      float p1 = nv * ldf(Wo, t * 2 + 1, isf32);
      float vv = (t & 1) ? p1 : p0;
      float ww = (t & 1) ? p0 : p1;
      vv += __shfl_xor(ww, 1);
      #pragma unroll
      for (int off = 2; off < 64; off <<= 1) vv += __shfl_xor(vv, off);
      if (t < 2) stf(outh, (size_t)n * 2 + t, vv + ldf(bo, t, isf32), isf32);
    }
  }
}

// ---------------- edge head v6: v3 structure, DS-free inner loop --------------
// Original edge order (contiguous stores), 2-edge pipeline, fixed 16 iters.
// (a) index loads scalarized via readfirstlane -> s_load; (b) alpha broadcast
// via v_readlane into SGPRs; (c) final 64-lane reduce via DPP butterfly;
// (d) precomputed 1/sum (no division).
#define EPW 32
__global__ __launch_bounds__(256) void edge_head6(
    const int* __restrict__ ei, const float* __restrict__ asrc, const float* __restrict__ adst,
    const float* __restrict__ rsumv,
    const ushort_t* __restrict__ pq, const void* __restrict__ Wm1,
    const void* __restrict__ bm1, const void* __restrict__ Wm2,
    const void* __restrict__ bm2, void* __restrict__ out,
    const int* __restrict__ dflag)
{
  int isf32 = *dflag;
  int lane = threadIdx.x & 63;
  int c0 = lane * 4;
  int h = lane & 7;
  float w1r[8][4], w2a[4], w2b[4], b1r[4];
  #pragma unroll
  for (int hh = 0; hh < 8; ++hh)
    #pragma unroll
    for (int j = 0; j < 4; ++j)
      w1r[hh][j] = ldf(Wm1, (64 + hh) * 256 + c0 + j, isf32);
  #pragma unroll
  for (int j = 0; j < 4; ++j) {
    w2a[j] = ldf(Wm2, (c0 + j) * 2 + 0, isf32);
    w2b[j] = ldf(Wm2, (c0 + j) * 2 + 1, isf32);
    b1r[j] = ldf(bm1, c0 + j, isf32);
  }
  float bo0 = ldf(bm2, 0, isf32), bo1 = ldf(bm2, 1, isf32);

  int wid = blockIdx.x * 4 + (threadIdx.x >> 6);
  int e0 = wid * EPW;                       // EPW*4=128 divides N_EDGES exactly
  for (int e = e0; e < e0 + EPW; e += 2) {
    int eu = __builtin_amdgcn_readfirstlane(e);     // uniform -> s_load of indices
    int sA = ei[eu],     dA = ei[N_EDGES + eu];
    int sB = ei[eu + 1], dB = ei[N_EDGES + eu + 1];
    float vA = asrc[sA * HEADS + h] + adst[dA * HEADS + h];
    float vB = asrc[sB * HEADS + h] + adst[dB * HEADS + h];
    float rsA = rsumv[dA * HEADS + h], rsB = rsumv[dB * HEADS + h];
    ushort4 pvA = *(const ushort4*)(pq + (size_t)sA * FDIM + c0);
    ushort4 qvA = *(const ushort4*)(pq + (size_t)dA * FDIM + 256 + c0);
    ushort4 pvB = *(const ushort4*)(pq + (size_t)sB * FDIM + c0);
    ushort4 qvB = *(const ushort4*)(pq + (size_t)dB * FDIM + 256 + c0);
    float aA = __expf(leakyf(vA)) * rsA;
    float aB = __expf(leakyf(vB)) * rsB;
    // alpha lives in lanes 0..7 (lane&7 == head); lift to SGPRs via readlane
    float alA[8], alB[8];
    #pragma unroll
    for (int hh = 0; hh < 8; ++hh) {
      alA[hh] = __int_as_float(__builtin_amdgcn_readlane(__float_as_int(aA), hh));
      alB[hh] = __int_as_float(__builtin_amdgcn_readlane(__float_as_int(aB), hh));
    }

    float accA0 = 0.f, accA1 = 0.f, accB0 = 0.f, accB1 = 0.f;
    float pA[4] = { bf2f(pvA.x), bf2f(pvA.y), bf2f(pvA.z), bf2f(pvA.w) };
    float qA[4] = { bf2f(qvA.x), bf2f(qvA.y), bf2f(qvA.z), bf2f(qvA.w) };
    float pB[4] = { bf2f(pvB.x), bf2f(pvB.y), bf2f(pvB.z), bf2f(pvB.w) };
    float qB[4] = { bf2f(qvB.x), bf2f(qvB.y), bf2f(qvB.z), bf2f(qvB.w) };
    #pragma unroll
    for (int j = 0; j < 4; ++j) {
      float hvA = pA[j] + qA[j] + b1r[j];
      float hvB = pB[j] + qB[j] + b1r[j];
      #pragma unroll
      for (int hh = 0; hh < 8; ++hh) {
        hvA += alA[hh] * w1r[hh][j];
        hvB += alB[hh] * w1r[hh][j];
      }
      hvA = fmaxf(hvA, 0.f);
      hvB = fmaxf(hvB, 0.f);
      accA0 += hvA * w2a[j]; accA1 += hvA * w2b[j];
      accB0 += hvB * w2a[j]; accB1 += hvB * w2b[j];
    }
    accA0 = dpp_sum64(accA0);
    accA1 = dpp_sum64(accA1);
    accB0 = dpp_sum64(accB0);
    accB1 = dpp_sum64(accB1);
    if (lane == 63) {
      stf(out, 100000 + (size_t)e * 2 + 0, accA0 + bo0, isf32);
      stf(out, 100000 + (size_t)e * 2 + 1, accA1 + bo1, isf32);
      stf(out, 100000 + (size_t)e * 2 + 2, accB0 + bo0, isf32);
      stf(out, 100000 + (size_t)e * 2 + 3, accB1 + bo1, isf32);
    }
  }
}

// ---------------- launch ----------------
extern "C" void kernel_launch(void* const* d_in, const int* in_sizes, int n_in,
                              void* d_out, int out_size, void* d_ws, size_t ws_size,
                              hipStream_t stream) {
  const void* x   = d_in[0];
  const int*  ei  = (const int*)d_in[1];
  const void* Wn  = d_in[4];
  const void* bn  = d_in[5];
  const void* Wr  = d_in[6];
  const void* br  = d_in[7];
  const void* W1  = d_in[8];
  const void* as1 = d_in[9];
  const void* ad1 = d_in[10];
  const void* bc1 = d_in[11];
  const void* W2  = d_in[12];
  const void* as2 = d_in[13];
  const void* ad2 = d_in[14];
  const void* bc2 = d_in[15];
  const void* W3  = d_in[16];
  const void* as3 = d_in[17];
  const void* ad3 = d_in[18];
  const void* bc3 = d_in[19];
  const void* Wo  = d_in[20];
  const void* bo  = d_in[21];
  const void* Wm1 = d_in[22];
  const void* bm1 = d_in[23];
  const void* Wm2 = d_in[24];
  const void* bm2 = d_in[25];

  char* ws = (char*)d_ws;
  size_t off = 0;
  auto take = [&](size_t bytes) -> char* {
    char* p = ws + off;
    off += (bytes + 255) & ~(size_t)255;
    return p;
  };
  ushort_t* h_bf   = (ushort_t*)take((size_t)NPAD * 64 * 2);       // enc out / node_embedding
  ushort_t* g_bf   = (ushort_t*)take((size_t)NPAD * FDIM * 2);     // gemm out / P|Q
  ushort_t* o_bf   = (ushort_t*)take((size_t)NPAD * FDIM * 2);     // layer out
  float*    asrc   = (float*)take((size_t)N_NODES * HEADS * 4);
  float*    adst   = (float*)take((size_t)N_NODES * HEADS * 4);
  float*    sumv   = (float*)take((size_t)N_NODES * HEADS * 4);
  int*      rowptr = (int*)take((size_t)(N_NODES + 1) * 4);
  int*      csr_src= (int*)take((size_t)EPRIME * 4);
  int*      deg    = (int*)take((size_t)N_NODES * 4);
  int*      fillc  = (int*)take((size_t)N_NODES * 4);
  int*      dflag  = (int*)take(256);
  ushort_t* WT1    = (ushort_t*)take((size_t)512 * 64 * 2);        // W1^T  [512][64]
  ushort_t* WT2    = (ushort_t*)take((size_t)512 * 512 * 2);       // W2^T  [512][512]
  ushort_t* WT3    = (ushort_t*)take((size_t)512 * 512 * 2);       // W3^T  [512][512]
  ushort_t* WTPQ   = (ushort_t*)take((size_t)512 * 64 * 2);        // [P^T ; Q^T] combined
  ushort_t* attv   = (ushort_t*)take((size_t)6 * 512 * 2);         // packed a_src/a_dst x3

  dim3 b256(256);
  const int MB = NPAD / 128;  // 391

  detect_dtype<<<dim3(1), dim3(64), 0, stream>>>(Wn, dflag);

  // weight conversion (transpose to [n][k], bf16); W1 is [64,512] -> K=64
  convert_wt<<<dim3(128),  b256, 0, stream>>>(W1, WT1, 64, 512, 0, dflag);
  convert_wt<<<dim3(1024), b256, 0, stream>>>(W2, WT2, 512, 512, 0, dflag);
  convert_wt<<<dim3(1024), b256, 0, stream>>>(W3, WT3, 512, 512, 0, dflag);
  convert_wt<<<dim3(64),   b256, 0, stream>>>(Wm1, WTPQ,            64, 256, 0,  dflag);
  convert_wt<<<dim3(64),   b256, 0, stream>>>(Wm1, WTPQ + 256 * 64, 64, 256, 72, dflag);
  convert_att<<<dim3(12),  b256, 0, stream>>>(as1, ad1, as2, ad2, as3, ad3, attv, dflag);

  // CSR build
  init_deg<<<dim3((N_NODES + 255) / 256), b256, 0, stream>>>(deg, fillc);
  count_edges<<<dim3((N_EDGES + 255) / 256), b256, 0, stream>>>(ei, deg);
  scan1024<<<dim3(1), dim3(1024), 0, stream>>>(deg, rowptr);
  fill_csr<<<dim3((EPRIME + 255) / 256), b256, 0, stream>>>(ei, rowptr, fillc, csr_src);

  // node encoder
  encode_h<<<dim3((N_NODES * 64 + 255) / 256), b256, 0, stream>>>(x, Wn, bn, h_bf, dflag);

  // ---- GAT layer 1 (in: h_bf [NPAD,64]); attn fused in gemm epilogue ----
  gemm_bt<<<dim3(MB, 4), b256, 0, stream>>>(h_bf, WT1, g_bf, 64, 512,
                                            attv, asrc, adst);
  aggregate<<<dim3(N_NODES), b256, 0, stream>>>(rowptr, csr_src, asrc, adst, sumv,
                                                g_bf, x, Wr, br, bc1, o_bf, 0,
                                                nullptr, nullptr, d_out, dflag);

  // ---- GAT layer 2 ----
  gemm_bt<<<dim3(MB, 4), b256, 0, stream>>>(o_bf, WT2, g_bf, 512, 512,
                                            attv + 1024, asrc, adst);
  aggregate<<<dim3(N_NODES), b256, 0, stream>>>(rowptr, csr_src, asrc, adst, sumv,
                                                g_bf, x, Wr, br, bc2, o_bf, 0,
                                                nullptr, nullptr, d_out, dflag);

  // ---- GAT layer 3 (mean over heads -> ne in h_bf; node head fused) ----
  gemm_bt<<<dim3(MB, 4), b256, 0, stream>>>(o_bf, WT3, g_bf, 512, 512,
                                            attv + 2048, asrc, adst);
  aggregate<<<dim3(N_NODES), b256, 0, stream>>>(rowptr, csr_src, asrc, adst, sumv,
                                                g_bf, x, Wr, br, bc3, h_bf, 1,
                                                Wo, bo, d_out, dflag);

  // ---- edge head: P|Q in one gemm, then per-edge MLP (DS-free) ----
  gemm_bt<<<dim3(MB, 4), b256, 0, stream>>>(h_bf, WTPQ, g_bf, 64, 512,
                                            nullptr, nullptr, nullptr);
  edge_head6<<<dim3(N_EDGES / (EPW * 4)), b256, 0, stream>>>(ei, asrc, adst, sumv, g_bf,
                                                             Wm1, bm1, Wm2, bm2,
                                                             d_out, dflag);
}

// Round 5
// 1029.725 us; speedup vs baseline: 1.2816x; 1.0439x over previous
//
#include <hip/hip_runtime.h>
#include <hip/hip_bf16.h>
#include <math.h>

#define N_NODES 50000
#define NPAD    50048                  // N_NODES rounded up to 128 (gemm tiles, no guards)
#define N_EDGES 800000
#define EPRIME  (N_EDGES + N_NODES)   // edges + self loops
#define HEADS 8
#define CH 64
#define FDIM 512                       // HEADS*CH

typedef unsigned short ushort_t;
typedef __attribute__((ext_vector_type(8))) short bf16x8_t;  // 8 bf16 = 4 VGPRs
typedef __attribute__((ext_vector_type(4))) float f32x4_t;

__device__ __forceinline__ float bf2f(unsigned short u) {
  union { unsigned int i; float f; } v; v.i = ((unsigned int)u) << 16; return v.f;
}
__device__ __forceinline__ unsigned short f2bf(float f) {
  union { float f; unsigned int i; } v; v.f = f;
  unsigned int x = v.i;
  return (unsigned short)((x + 0x7fffu + ((x >> 16) & 1u)) >> 16);  // RNE
}
__device__ __forceinline__ float ldf(const void* p, size_t idx, int isf32) {
  return isf32 ? ((const float*)p)[idx] : bf2f(((const ushort_t*)p)[idx]);
}
__device__ __forceinline__ void stf(void* p, size_t idx, float v, int isf32) {
  if (isf32) ((float*)p)[idx] = v;
  else       ((ushort_t*)p)[idx] = f2bf(v);
}
__device__ __forceinline__ float leakyf(float v) { return v >= 0.f ? v : 0.2f * v; }
__device__ __forceinline__ float eluf(float v)   { return v > 0.f ? v : expm1f(v); }

// wave64 sum via DPP butterfly (LLVM AtomicOptimizer sequence); full sum valid
// in lanes 48..63 (use lane 63). Pure VALU — no DS pipe, no LDS.
__device__ __forceinline__ float dpp_sum64(float x) {
  x += __int_as_float(__builtin_amdgcn_update_dpp(0, __float_as_int(x), 0xB1, 0xf, 0xf, false)); // quad_perm [1,0,3,2]
  x += __int_as_float(__builtin_amdgcn_update_dpp(0, __float_as_int(x), 0x4E, 0xf, 0xf, false)); // quad_perm [2,3,0,1]
  x += __int_as_float(__builtin_amdgcn_update_dpp(0, __float_as_int(x), 0x141, 0xf, 0xf, false)); // row_half_mirror
  x += __int_as_float(__builtin_amdgcn_update_dpp(0, __float_as_int(x), 0x140, 0xf, 0xf, false)); // row_mirror
  x += __int_as_float(__builtin_amdgcn_update_dpp(0, __float_as_int(x), 0x142, 0xa, 0xf, false)); // row_bcast:15 rows 1,3
  x += __int_as_float(__builtin_amdgcn_update_dpp(0, __float_as_int(x), 0x143, 0xc, 0xf, false)); // row_bcast:31 rows 2,3
  return x;
}

// async global->LDS, 16B per lane; LDS dest = wave-uniform base + lane*16
typedef const __attribute__((address_space(1))) unsigned int* gas1_t;
typedef __attribute__((address_space(3))) unsigned int* las3_t;
__device__ __forceinline__ void gll16(const ushort_t* g, ushort_t* l) {
  __builtin_amdgcn_global_load_lds((gas1_t)g, (las3_t)l, 16, 0, 0);
}

// ---------------- dtype detector ----------------
__global__ void detect_dtype(const void* Wn, int* flag) {
  if (blockIdx.x == 0 && threadIdx.x == 0) {
    const ushort_t* u = (const ushort_t*)Wn;
    int extreme = 0;
    for (int i = 0; i < 384; ++i) {
      float v = fabsf(bf2f(u[i]));
      if (v != 0.f && (v > 16.f || v < 6.1e-5f)) extreme++;
    }
    *flag = (extreme >= 20) ? 1 : 0;
  }
}

// ---------------- weight transpose-convert: dst[n*K+k] = src[(boff+k)*N + n] ----
__global__ void convert_wt(const void* __restrict__ src, ushort_t* __restrict__ dst,
                           int K, int N, int boff, const int* __restrict__ dflag) {
  int isf32 = *dflag;
  int tid = blockIdx.x * blockDim.x + threadIdx.x;
  if (tid >= N * K) return;
  int n = tid / K, k = tid % K;
  dst[tid] = f2bf(ldf(src, (size_t)(boff + k) * N + n, isf32));
}

// pack 6 attention vectors (3 layers x {a_src, a_dst}, 512 elems each) to bf16
__global__ void convert_att(const void* s1, const void* d1, const void* s2, const void* d2,
                            const void* s3, const void* d3, ushort_t* __restrict__ dst,
                            const int* __restrict__ dflag) {
  int isf32 = *dflag;
  int tid = blockIdx.x * blockDim.x + threadIdx.x;
  if (tid >= 6 * 512) return;
  int which = tid >> 9, idx = tid & 511;
  const void* p = which == 0 ? s1 : which == 1 ? d1 : which == 2 ? s2
                : which == 3 ? d2 : which == 4 ? s3 : d3;
  dst[tid] = f2bf(ldf(p, idx, isf32));
}

// ---------------- CSR build ----------------
__global__ void init_deg(int* deg, int* fill) {
  int n = blockIdx.x * blockDim.x + threadIdx.x;
  if (n < N_NODES) { deg[n] = 1; fill[n] = 0; }   // 1 = self loop
}

__global__ void count_edges(const int* __restrict__ ei, int* deg) {
  int e = blockIdx.x * blockDim.x + threadIdx.x;
  if (e < N_EDGES) atomicAdd(&deg[ei[N_EDGES + e]], 1);
}

// parallel exclusive scan of deg[0..N_NODES) -> rowptr; 1 block x 1024 threads.
__global__ __launch_bounds__(1024) void scan1024(const int* __restrict__ deg,
                                                 int* __restrict__ rowptr) {
  const int CHUNK = (N_NODES + 1023) / 1024;   // 49
  int t = threadIdx.x;
  int wave = t >> 6, lane = t & 63;
  int lo = t * CHUNK;
  int hi = lo + CHUNK; if (hi > N_NODES) hi = N_NODES;
  int s = 0;
  for (int i = lo; i < hi; ++i) s += deg[i];
  int inc = s;
  #pragma unroll
  for (int off = 1; off < 64; off <<= 1) {
    int u = __shfl_up(inc, off);
    if (lane >= off) inc += u;
  }
  __shared__ int wsum[16];
  if (lane == 63) wsum[wave] = inc;
  __syncthreads();
  int wbase = 0;
  for (int w = 0; w < wave; ++w) wbase += wsum[w];
  int run = wbase + inc - s;                   // exclusive prefix for this thread
  for (int i = lo; i < hi; ++i) { rowptr[i] = run; run += deg[i]; }
  if (t == 1023) rowptr[N_NODES] = run;
}

__global__ void fill_csr(const int* __restrict__ ei, const int* __restrict__ rowptr,
                         int* fill, int* __restrict__ csr_src) {
  int e = blockIdx.x * blockDim.x + threadIdx.x;
  if (e >= EPRIME) return;
  int s, d;
  if (e < N_EDGES) { s = ei[e]; d = ei[N_EDGES + e]; }
  else             { s = d = e - N_EDGES; }
  int pos = rowptr[d] + atomicAdd(&fill[d], 1);
  csr_src[pos] = s;
}

// ---------------- node encoder ----------------
__global__ void encode_h(const void* __restrict__ x, const void* __restrict__ Wn,
                         const void* __restrict__ bn, ushort_t* __restrict__ h,
                         const int* __restrict__ dflag) {
  int isf32 = *dflag;
  int tid = blockIdx.x * blockDim.x + threadIdx.x;
  if (tid >= N_NODES * 64) return;
  int n = tid >> 6, j = tid & 63;
  float x0 = ldf(x, n * 3 + 0, isf32), x1 = ldf(x, n * 3 + 1, isf32), x2 = ldf(x, n * 3 + 2, isf32);
  float v = x0 * ldf(Wn, j, isf32) + x1 * ldf(Wn, 64 + j, isf32)
          + x2 * ldf(Wn, 128 + j, isf32) + ldf(bn, j, isf32);
  h[tid] = f2bf(v);
}

// ---------------- MFMA GEMM + fused attn-coef epilogue ------------------------
__global__ __launch_bounds__(256) void gemm_bt(
    const ushort_t* __restrict__ A, const ushort_t* __restrict__ BT,
    ushort_t* __restrict__ C, int K, int ldc,
    const ushort_t* __restrict__ att, float* __restrict__ asrc, float* __restrict__ adst)
{
  __shared__ __align__(16) ushort_t As[128][32];
  __shared__ __align__(16) ushort_t Bs[128][32];
  int tid = threadIdx.x;
  int wave = tid >> 6, lane = tid & 63;
  int wr = wave >> 1, wc = wave & 1;
  int row0 = blockIdx.x * 128, col0 = blockIdx.y * 128;
  int fm = lane & 15, fq = lane >> 4;

  f32x4_t acc[4][4];
  #pragma unroll
  for (int i = 0; i < 4; ++i)
    #pragma unroll
    for (int j = 0; j < 4; ++j) acc[i][j] = (f32x4_t){0.f, 0.f, 0.f, 0.f};

  int srow = wave * 32 + (lane >> 2);
  int skel = (lane & 3) * 8;
  const ushort_t* aG0 = A  + (size_t)(row0 + srow) * K + skel;
  const ushort_t* aG1 = A  + (size_t)(row0 + srow + 16) * K + skel;
  const ushort_t* bG0 = BT + (size_t)(col0 + srow) * K + skel;
  const ushort_t* bG1 = BT + (size_t)(col0 + srow + 16) * K + skel;
  ushort_t* aL0 = &As[wave * 32][0];
  ushort_t* aL1 = &As[wave * 32 + 16][0];
  ushort_t* bL0 = &Bs[wave * 32][0];
  ushort_t* bL1 = &Bs[wave * 32 + 16][0];

  for (int k0 = 0; k0 < K; k0 += 32) {
    gll16(aG0 + k0, aL0);
    gll16(aG1 + k0, aL1);
    gll16(bG0 + k0, bL0);
    gll16(bG1 + k0, bL1);
    __syncthreads();
    bf16x8_t af[4], bfr[4];
    #pragma unroll
    for (int i = 0; i < 4; ++i) af[i]  = *(const bf16x8_t*)&As[64 * wr + 16 * i + fm][fq * 8];
    #pragma unroll
    for (int j = 0; j < 4; ++j) bfr[j] = *(const bf16x8_t*)&Bs[64 * wc + 16 * j + fm][fq * 8];
    #pragma unroll
    for (int i = 0; i < 4; ++i)
      #pragma unroll
      for (int j = 0; j < 4; ++j)
        acc[i][j] = __builtin_amdgcn_mfma_f32_16x16x32_bf16(af[i], bfr[j], acc[i][j], 0, 0, 0);
    __syncthreads();
  }

  int do_att = (att != nullptr);
  int head = 2 * blockIdx.y + wc;
  float sa[4], sd[4];
  if (do_att) {
    #pragma unroll
    for (int j = 0; j < 4; ++j) {
      int ch = 16 * j + fm;
      sa[j] = bf2f(att[head * CH + ch]);
      sd[j] = bf2f(att[512 + head * CH + ch]);
    }
  }

  // C/D layout: col = lane&15, row = (lane>>4)*4 + reg
  #pragma unroll
  for (int i = 0; i < 4; ++i) {
    int rowb = row0 + 64 * wr + 16 * i + fq * 4;
    #pragma unroll
    for (int r = 0; r < 4; ++r) {
      int row = rowb + r;
      float ss = 0.f, dd = 0.f;
      #pragma unroll
      for (int j = 0; j < 4; ++j) {
        ushort_t uv = f2bf(acc[i][j][r]);
        C[(size_t)row * ldc + col0 + 64 * wc + 16 * j + fm] = uv;
        if (do_att) {
          float cv = bf2f(uv);
          ss += cv * sa[j];
          dd += cv * sd[j];
        }
      }
      if (do_att) {
        #pragma unroll
        for (int off = 8; off > 0; off >>= 1) {
          ss += __shfl_down(ss, off);
          dd += __shfl_down(dd, off);
        }
        if (fm == 0 && row < N_NODES) {
          asrc[row * HEADS + head] = ss;
          adst[row * HEADS + head] = dd;
        }
      }
    }
  }
}

// ---------------- aggregation v2: wave-per-edge-subset, 16B g loads -----------
// 4 waves split the edge list (interleaved); each wave covers ALL 512 channels
// (8 ch/lane, one bf16x8 load per edge, 1 exp per edge, 1 asrc gather per edge,
// scalarized csr index). Partials combined via 8KB LDS reduce.
// sumv stores the RECIPROCAL 1/l (consumed only by edge_head as a multiply).
__global__ __launch_bounds__(256) void aggregate2(
    const int* __restrict__ rowptr, const int* __restrict__ csr_src,
    const float* __restrict__ asrc, const float* __restrict__ adst,
    float* __restrict__ sumv,
    const ushort_t* __restrict__ g,
    const void* __restrict__ x, const void* __restrict__ Wr,
    const void* __restrict__ br, const void* __restrict__ bc,
    ushort_t* __restrict__ out, int mean_mode,
    const void* __restrict__ Wo, const void* __restrict__ bo,
    void* __restrict__ outh, const int* __restrict__ dflag)
{
  int isf32 = *dflag;
  __shared__ float red[4][512];
  __shared__ float lred[4][8];
  __shared__ float sx[3];
  int n = blockIdx.x;
  int t = threadIdx.x;
  int wave = t >> 6, lane = t & 63;
  if (t < 3) sx[t] = ldf(x, n * 3 + t, isf32);

  int ch0 = lane * 8;        // 8 contiguous channels
  int hh  = lane >> 3;       // head owning these channels
  int start = rowptr[n], end = rowptr[n + 1];
  float ad = adst[n * HEADS + hh];

  float acc[8];
  #pragma unroll
  for (int k = 0; k < 8; ++k) acc[k] = 0.f;
  float l = 0.f;

  int i = start + wave;
  for (; i + 4 < end; i += 8) {           // 2 edges in flight
    int iu0 = __builtin_amdgcn_readfirstlane(i);
    int iu1 = __builtin_amdgcn_readfirstlane(i + 4);
    int s0 = csr_src[iu0];
    int s1 = csr_src[iu1];
    float e0 = asrc[s0 * HEADS + hh] + ad;
    float e1 = asrc[s1 * HEADS + hh] + ad;
    bf16x8_t gv0 = *(const bf16x8_t*)(g + (size_t)s0 * FDIM + ch0);
    bf16x8_t gv1 = *(const bf16x8_t*)(g + (size_t)s1 * FDIM + ch0);
    float p0 = __expf(leakyf(e0));
    float p1 = __expf(leakyf(e1));
    l += p0 + p1;
    #pragma unroll
    for (int k = 0; k < 8; ++k)
      acc[k] += p0 * bf2f((ushort_t)gv0[k]) + p1 * bf2f((ushort_t)gv1[k]);
  }
  if (i < end) {
    int iu0 = __builtin_amdgcn_readfirstlane(i);
    int s0 = csr_src[iu0];
    float e0 = asrc[s0 * HEADS + hh] + ad;
    bf16x8_t gv0 = *(const bf16x8_t*)(g + (size_t)s0 * FDIM + ch0);
    float p0 = __expf(leakyf(e0));
    l += p0;
    #pragma unroll
    for (int k = 0; k < 8; ++k) acc[k] += p0 * bf2f((ushort_t)gv0[k]);
  }

  #pragma unroll
  for (int k = 0; k < 8; ++k) red[wave][ch0 + k] = acc[k];
  if ((lane & 7) == 0) lred[wave][hh] = l;
  __syncthreads();

  // combine: thread t covers channels (2t, 2t+1), head t>>5 (old layout)
  int c0 = t * 2;
  int h  = t >> 5;
  float a0 = red[0][c0]     + red[1][c0]     + red[2][c0]     + red[3][c0];
  float a1 = red[0][c0 + 1] + red[1][c0 + 1] + red[2][c0 + 1] + red[3][c0 + 1];
  float lt = lred[0][h] + lred[1][h] + lred[2][h] + lred[3][h];
  a0 /= lt;
  a1 /= lt;
  if ((t & 31) == 0) sumv[n * HEADS + h] = 1.f / lt;   // reciprocal

  if (!mean_mode) {
    float r0 = sx[0] * ldf(Wr, c0, isf32)         + sx[1] * ldf(Wr, 512 + c0, isf32)
             + sx[2] * ldf(Wr, 1024 + c0, isf32)  + ldf(br, c0, isf32);
    float r1 = sx[0] * ldf(Wr, c0 + 1, isf32)     + sx[1] * ldf(Wr, 512 + c0 + 1, isf32)
             + sx[2] * ldf(Wr, 1024 + c0 + 1, isf32) + ldf(br, c0 + 1, isf32);
    unsigned int o0 = f2bf(eluf(a0 + ldf(bc, c0, isf32)) + r0);
    unsigned int o1 = f2bf(eluf(a1 + ldf(bc, c0 + 1, isf32)) + r1);
    *(unsigned int*)(out + (size_t)n * FDIM + c0) = o0 | (o1 << 16);
  } else {
    __syncthreads();                      // red[] reads above must complete
    red[0][c0] = a0; red[0][c0 + 1] = a1;
    __syncthreads();
    if (t < 64) {                               // wave 0, uniform branch
      float tot = 0.f;
      #pragma unroll
      for (int hh2 = 0; hh2 < 8; ++hh2) tot += red[0][t + 64 * hh2];
      ushort_t uv = f2bf(eluf(tot * 0.125f + ldf(bc, t, isf32)));
      out[(size_t)n * CH + t] = uv;
      // fused node head on the bf16-rounded ne value (matches old node_head)
      float nv = bf2f(uv);
      float p0 = nv * ldf(Wo, t * 2 + 0, isf32);
      float p1 = nv * ldf(Wo, t * 2 + 1, isf32);
      float vv = (t & 1) ? p1 : p0;
      float ww = (t & 1) ? p0 : p1;
      vv += __shfl_xor(ww, 1);
      #pragma unroll
      for (int off = 2; off < 64; off <<= 1) vv += __shfl_xor(vv, off);
      if (t < 2) stf(outh, (size_t)n * 2 + t, vv + ldf(bo, t, isf32), isf32);
    }
  }
}

// ---------------- edge head v6: v3 structure, DS-free inner loop --------------
#define EPW 32
__global__ __launch_bounds__(256) void edge_head6(
    const int* __restrict__ ei, const float* __restrict__ asrc, const float* __restrict__ adst,
    const float* __restrict__ rsumv,
    const ushort_t* __restrict__ pq, const void* __restrict__ Wm1,
    const void* __restrict__ bm1, const void* __restrict__ Wm2,
    const void* __restrict__ bm2, void* __restrict__ out,
    const int* __restrict__ dflag)
{
  int isf32 = *dflag;
  int lane = threadIdx.x & 63;
  int c0 = lane * 4;
  int h = lane & 7;
  float w1r[8][4], w2a[4], w2b[4], b1r[4];
  #pragma unroll
  for (int hh = 0; hh < 8; ++hh)
    #pragma unroll
    for (int j = 0; j < 4; ++j)
      w1r[hh][j] = ldf(Wm1, (64 + hh) * 256 + c0 + j, isf32);
  #pragma unroll
  for (int j = 0; j < 4; ++j) {
    w2a[j] = ldf(Wm2, (c0 + j) * 2 + 0, isf32);
    w2b[j] = ldf(Wm2, (c0 + j) * 2 + 1, isf32);
    b1r[j] = ldf(bm1, c0 + j, isf32);
  }
  float bo0 = ldf(bm2, 0, isf32), bo1 = ldf(bm2, 1, isf32);

  int wid = blockIdx.x * 4 + (threadIdx.x >> 6);
  int e0 = wid * EPW;                       // EPW*4=128 divides N_EDGES exactly
  for (int e = e0; e < e0 + EPW; e += 2) {
    int eu = __builtin_amdgcn_readfirstlane(e);     // uniform -> s_load of indices
    int sA = ei[eu],     dA = ei[N_EDGES + eu];
    int sB = ei[eu + 1], dB = ei[N_EDGES + eu + 1];
    float vA = asrc[sA * HEADS + h] + adst[dA * HEADS + h];
    float vB = asrc[sB * HEADS + h] + adst[dB * HEADS + h];
    float rsA = rsumv[dA * HEADS + h], rsB = rsumv[dB * HEADS + h];
    ushort4 pvA = *(const ushort4*)(pq + (size_t)sA * FDIM + c0);
    ushort4 qvA = *(const ushort4*)(pq + (size_t)dA * FDIM + 256 + c0);
    ushort4 pvB = *(const ushort4*)(pq + (size_t)sB * FDIM + c0);
    ushort4 qvB = *(const ushort4*)(pq + (size_t)dB * FDIM + 256 + c0);
    float aA = __expf(leakyf(vA)) * rsA;
    float aB = __expf(leakyf(vB)) * rsB;
    // alpha lives in lanes 0..7 (lane&7 == head); lift to SGPRs via readlane
    float alA[8], alB[8];
    #pragma unroll
    for (int hh = 0; hh < 8; ++hh) {
      alA[hh] = __int_as_float(__builtin_amdgcn_readlane(__float_as_int(aA), hh));
      alB[hh] = __int_as_float(__builtin_amdgcn_readlane(__float_as_int(aB), hh));
    }

    float accA0 = 0.f, accA1 = 0.f, accB0 = 0.f, accB1 = 0.f;
    float pA[4] = { bf2f(pvA.x), bf2f(pvA.y), bf2f(pvA.z), bf2f(pvA.w) };
    float qA[4] = { bf2f(qvA.x), bf2f(qvA.y), bf2f(qvA.z), bf2f(qvA.w) };
    float pB[4] = { bf2f(pvB.x), bf2f(pvB.y), bf2f(pvB.z), bf2f(pvB.w) };
    float qB[4] = { bf2f(qvB.x), bf2f(qvB.y), bf2f(qvB.z), bf2f(qvB.w) };
    #pragma unroll
    for (int j = 0; j < 4; ++j) {
      float hvA = pA[j] + qA[j] + b1r[j];
      float hvB = pB[j] + qB[j] + b1r[j];
      #pragma unroll
      for (int hh = 0; hh < 8; ++hh) {
        hvA += alA[hh] * w1r[hh][j];
        hvB += alB[hh] * w1r[hh][j];
      }
      hvA = fmaxf(hvA, 0.f);
      hvB = fmaxf(hvB, 0.f);
      accA0 += hvA * w2a[j]; accA1 += hvA * w2b[j];
      accB0 += hvB * w2a[j]; accB1 += hvB * w2b[j];
    }
    accA0 = dpp_sum64(accA0);
    accA1 = dpp_sum64(accA1);
    accB0 = dpp_sum64(accB0);
    accB1 = dpp_sum64(accB1);
    if (lane == 63) {
      stf(out, 100000 + (size_t)e * 2 + 0, accA0 + bo0, isf32);
      stf(out, 100000 + (size_t)e * 2 + 1, accA1 + bo1, isf32);
      stf(out, 100000 + (size_t)e * 2 + 2, accB0 + bo0, isf32);
      stf(out, 100000 + (size_t)e * 2 + 3, accB1 + bo1, isf32);
    }
  }
}

// ---------------- launch ----------------
extern "C" void kernel_launch(void* const* d_in, const int* in_sizes, int n_in,
                              void* d_out, int out_size, void* d_ws, size_t ws_size,
                              hipStream_t stream) {
  const void* x   = d_in[0];
  const int*  ei  = (const int*)d_in[1];
  const void* Wn  = d_in[4];
  const void* bn  = d_in[5];
  const void* Wr  = d_in[6];
  const void* br  = d_in[7];
  const void* W1  = d_in[8];
  const void* as1 = d_in[9];
  const void* ad1 = d_in[10];
  const void* bc1 = d_in[11];
  const void* W2  = d_in[12];
  const void* as2 = d_in[13];
  const void* ad2 = d_in[14];
  const void* bc2 = d_in[15];
  const void* W3  = d_in[16];
  const void* as3 = d_in[17];
  const void* ad3 = d_in[18];
  const void* bc3 = d_in[19];
  const void* Wo  = d_in[20];
  const void* bo  = d_in[21];
  const void* Wm1 = d_in[22];
  const void* bm1 = d_in[23];
  const void* Wm2 = d_in[24];
  const void* bm2 = d_in[25];

  char* ws = (char*)d_ws;
  size_t off = 0;
  auto take = [&](size_t bytes) -> char* {
    char* p = ws + off;
    off += (bytes + 255) & ~(size_t)255;
    return p;
  };
  ushort_t* h_bf   = (ushort_t*)take((size_t)NPAD * 64 * 2);       // enc out / node_embedding
  ushort_t* g_bf   = (ushort_t*)take((size_t)NPAD * FDIM * 2);     // gemm out / P|Q
  ushort_t* o_bf   = (ushort_t*)take((size_t)NPAD * FDIM * 2);     // layer out
  float*    asrc   = (float*)take((size_t)N_NODES * HEADS * 4);
  float*    adst   = (float*)take((size_t)N_NODES * HEADS * 4);
  float*    sumv   = (float*)take((size_t)N_NODES * HEADS * 4);
  int*      rowptr = (int*)take((size_t)(N_NODES + 1) * 4);
  int*      csr_src= (int*)take((size_t)EPRIME * 4);
  int*      deg    = (int*)take((size_t)N_NODES * 4);
  int*      fillc  = (int*)take((size_t)N_NODES * 4);
  int*      dflag  = (int*)take(256);
  ushort_t* WT1    = (ushort_t*)take((size_t)512 * 64 * 2);        // W1^T  [512][64]
  ushort_t* WT2    = (ushort_t*)take((size_t)512 * 512 * 2);       // W2^T  [512][512]
  ushort_t* WT3    = (ushort_t*)take((size_t)512 * 512 * 2);       // W3^T  [512][512]
  ushort_t* WTPQ   = (ushort_t*)take((size_t)512 * 64 * 2);        // [P^T ; Q^T] combined
  ushort_t* attv   = (ushort_t*)take((size_t)6 * 512 * 2);         // packed a_src/a_dst x3

  dim3 b256(256);
  const int MB = NPAD / 128;  // 391

  detect_dtype<<<dim3(1), dim3(64), 0, stream>>>(Wn, dflag);

  // weight conversion (transpose to [n][k], bf16); W1 is [64,512] -> K=64
  convert_wt<<<dim3(128),  b256, 0, stream>>>(W1, WT1, 64, 512, 0, dflag);
  convert_wt<<<dim3(1024), b256, 0, stream>>>(W2, WT2, 512, 512, 0, dflag);
  convert_wt<<<dim3(1024), b256, 0, stream>>>(W3, WT3, 512, 512, 0, dflag);
  convert_wt<<<dim3(64),   b256, 0, stream>>>(Wm1, WTPQ,            64, 256, 0,  dflag);
  convert_wt<<<dim3(64),   b256, 0, stream>>>(Wm1, WTPQ + 256 * 64, 64, 256, 72, dflag);
  convert_att<<<dim3(12),  b256, 0, stream>>>(as1, ad1, as2, ad2, as3, ad3, attv, dflag);

  // CSR build
  init_deg<<<dim3((N_NODES + 255) / 256), b256, 0, stream>>>(deg, fillc);
  count_edges<<<dim3((N_EDGES + 255) / 256), b256, 0, stream>>>(ei, deg);
  scan1024<<<dim3(1), dim3(1024), 0, stream>>>(deg, rowptr);
  fill_csr<<<dim3((EPRIME + 255) / 256), b256, 0, stream>>>(ei, rowptr, fillc, csr_src);

  // node encoder
  encode_h<<<dim3((N_NODES * 64 + 255) / 256), b256, 0, stream>>>(x, Wn, bn, h_bf, dflag);

  // ---- GAT layer 1 (in: h_bf [NPAD,64]); attn fused in gemm epilogue ----
  gemm_bt<<<dim3(MB, 4), b256, 0, stream>>>(h_bf, WT1, g_bf, 64, 512,
                                            attv, asrc, adst);
  aggregate2<<<dim3(N_NODES), b256, 0, stream>>>(rowptr, csr_src, asrc, adst, sumv,
                                                 g_bf, x, Wr, br, bc1, o_bf, 0,
                                                 nullptr, nullptr, d_out, dflag);

  // ---- GAT layer 2 ----
  gemm_bt<<<dim3(MB, 4), b256, 0, stream>>>(o_bf, WT2, g_bf, 512, 512,
                                            attv + 1024, asrc, adst);
  aggregate2<<<dim3(N_NODES), b256, 0, stream>>>(rowptr, csr_src, asrc, adst, sumv,
                                                 g_bf, x, Wr, br, bc2, o_bf, 0,
                                                 nullptr, nullptr, d_out, dflag);

  // ---- GAT layer 3 (mean over heads -> ne in h_bf; node head fused) ----
  gemm_bt<<<dim3(MB, 4), b256, 0, stream>>>(o_bf, WT3, g_bf, 512, 512,
                                            attv + 2048, asrc, adst);
  aggregate2<<<dim3(N_NODES), b256, 0, stream>>>(rowptr, csr_src, asrc, adst, sumv,
                                                 g_bf, x, Wr, br, bc3, h_bf, 1,
                                                 Wo, bo, d_out, dflag);

  // ---- edge head: P|Q in one gemm, then per-edge MLP (DS-free) ----
  gemm_bt<<<dim3(MB, 4), b256, 0, stream>>>(h_bf, WTPQ, g_bf, 64, 512,
                                            nullptr, nullptr, nullptr);
  edge_head6<<<dim3(N_EDGES / (EPW * 4)), b256, 0, stream>>>(ei, asrc, adst, sumv, g_bf,
                                                             Wm1, bm1, Wm2, bm2,
                                                             d_out, dflag);
}

// Round 6
// 1021.202 us; speedup vs baseline: 1.2923x; 1.0083x over previous
//
#include <hip/hip_runtime.h>
#include <hip/hip_bf16.h>
#include <math.h>

#define N_NODES 50000
#define NPAD    50048                  // N_NODES rounded up to 128 (gemm tiles, no guards)
#define N_EDGES 800000
#define EPRIME  (N_EDGES + N_NODES)   // edges + self loops
#define HEADS 8
#define CH 64
#define FDIM 512                       // HEADS*CH

typedef unsigned short ushort_t;
typedef __attribute__((ext_vector_type(8))) short bf16x8_t;  // 8 bf16 = 4 VGPRs
typedef __attribute__((ext_vector_type(4))) float f32x4_t;
typedef __attribute__((ext_vector_type(2))) float f32x2_t;   // packed fp32 (v_pk_*)

__device__ __forceinline__ float bf2f(unsigned short u) {
  union { unsigned int i; float f; } v; v.i = ((unsigned int)u) << 16; return v.f;
}
__device__ __forceinline__ unsigned short f2bf(float f) {
  union { float f; unsigned int i; } v; v.f = f;
  unsigned int x = v.i;
  return (unsigned short)((x + 0x7fffu + ((x >> 16) & 1u)) >> 16);  // RNE
}
__device__ __forceinline__ float ldf(const void* p, size_t idx, int isf32) {
  return isf32 ? ((const float*)p)[idx] : bf2f(((const ushort_t*)p)[idx]);
}
__device__ __forceinline__ void stf(void* p, size_t idx, float v, int isf32) {
  if (isf32) ((float*)p)[idx] = v;
  else       ((ushort_t*)p)[idx] = f2bf(v);
}
__device__ __forceinline__ float leakyf(float v) { return v >= 0.f ? v : 0.2f * v; }
__device__ __forceinline__ float eluf(float v)   { return v > 0.f ? v : expm1f(v); }

__device__ __forceinline__ f32x2_t sp2(float s) { return (f32x2_t){s, s}; }
// unpack a u32 holding two bf16 (lo = even channel, hi = odd channel) to f32x2
__device__ __forceinline__ f32x2_t bfpair(unsigned int u) {
  union { unsigned int i; float f; } lo, hi;
  lo.i = u << 16; hi.i = u & 0xffff0000u;
  return (f32x2_t){lo.f, hi.f};
}

// wave64 sum via DPP butterfly (LLVM AtomicOptimizer sequence); full sum valid
// in lanes 48..63 (use lane 63). Pure VALU — no DS pipe, no LDS.
__device__ __forceinline__ float dpp_sum64(float x) {
  x += __int_as_float(__builtin_amdgcn_update_dpp(0, __float_as_int(x), 0xB1, 0xf, 0xf, false)); // quad_perm [1,0,3,2]
  x += __int_as_float(__builtin_amdgcn_update_dpp(0, __float_as_int(x), 0x4E, 0xf, 0xf, false)); // quad_perm [2,3,0,1]
  x += __int_as_float(__builtin_amdgcn_update_dpp(0, __float_as_int(x), 0x141, 0xf, 0xf, false)); // row_half_mirror
  x += __int_as_float(__builtin_amdgcn_update_dpp(0, __float_as_int(x), 0x140, 0xf, 0xf, false)); // row_mirror
  x += __int_as_float(__builtin_amdgcn_update_dpp(0, __float_as_int(x), 0x142, 0xa, 0xf, false)); // row_bcast:15 rows 1,3
  x += __int_as_float(__builtin_amdgcn_update_dpp(0, __float_as_int(x), 0x143, 0xc, 0xf, false)); // row_bcast:31 rows 2,3
  return x;
}

// async global->LDS, 16B per lane; LDS dest = wave-uniform base + lane*16
typedef const __attribute__((address_space(1))) unsigned int* gas1_t;
typedef __attribute__((address_space(3))) unsigned int* las3_t;
__device__ __forceinline__ void gll16(const ushort_t* g, ushort_t* l) {
  __builtin_amdgcn_global_load_lds((gas1_t)g, (las3_t)l, 16, 0, 0);
}

// ---------------- dtype detector ----------------
__global__ void detect_dtype(const void* Wn, int* flag) {
  if (blockIdx.x == 0 && threadIdx.x == 0) {
    const ushort_t* u = (const ushort_t*)Wn;
    int extreme = 0;
    for (int i = 0; i < 384; ++i) {
      float v = fabsf(bf2f(u[i]));
      if (v != 0.f && (v > 16.f || v < 6.1e-5f)) extreme++;
    }
    *flag = (extreme >= 20) ? 1 : 0;
  }
}

// ---------------- weight transpose-convert: dst[n*K+k] = src[(boff+k)*N + n] ----
__global__ void convert_wt(const void* __restrict__ src, ushort_t* __restrict__ dst,
                           int K, int N, int boff, const int* __restrict__ dflag) {
  int isf32 = *dflag;
  int tid = blockIdx.x * blockDim.x + threadIdx.x;
  if (tid >= N * K) return;
  int n = tid / K, k = tid % K;
  dst[tid] = f2bf(ldf(src, (size_t)(boff + k) * N + n, isf32));
}

// pack 6 attention vectors (3 layers x {a_src, a_dst}, 512 elems each) to bf16
__global__ void convert_att(const void* s1, const void* d1, const void* s2, const void* d2,
                            const void* s3, const void* d3, ushort_t* __restrict__ dst,
                            const int* __restrict__ dflag) {
  int isf32 = *dflag;
  int tid = blockIdx.x * blockDim.x + threadIdx.x;
  if (tid >= 6 * 512) return;
  int which = tid >> 9, idx = tid & 511;
  const void* p = which == 0 ? s1 : which == 1 ? d1 : which == 2 ? s2
                : which == 3 ? d2 : which == 4 ? s3 : d3;
  dst[tid] = f2bf(ldf(p, idx, isf32));
}

// ---------------- CSR build ----------------
__global__ void init_deg(int* deg, int* fill) {
  int n = blockIdx.x * blockDim.x + threadIdx.x;
  if (n < N_NODES) { deg[n] = 1; fill[n] = 0; }   // 1 = self loop
}

__global__ void count_edges(const int* __restrict__ ei, int* deg) {
  int e = blockIdx.x * blockDim.x + threadIdx.x;
  if (e < N_EDGES) atomicAdd(&deg[ei[N_EDGES + e]], 1);
}

// parallel exclusive scan of deg[0..N_NODES) -> rowptr; 1 block x 1024 threads.
__global__ __launch_bounds__(1024) void scan1024(const int* __restrict__ deg,
                                                 int* __restrict__ rowptr) {
  const int CHUNK = (N_NODES + 1023) / 1024;   // 49
  int t = threadIdx.x;
  int wave = t >> 6, lane = t & 63;
  int lo = t * CHUNK;
  int hi = lo + CHUNK; if (hi > N_NODES) hi = N_NODES;
  int s = 0;
  for (int i = lo; i < hi; ++i) s += deg[i];
  int inc = s;
  #pragma unroll
  for (int off = 1; off < 64; off <<= 1) {
    int u = __shfl_up(inc, off);
    if (lane >= off) inc += u;
  }
  __shared__ int wsum[16];
  if (lane == 63) wsum[wave] = inc;
  __syncthreads();
  int wbase = 0;
  for (int w = 0; w < wave; ++w) wbase += wsum[w];
  int run = wbase + inc - s;                   // exclusive prefix for this thread
  for (int i = lo; i < hi; ++i) { rowptr[i] = run; run += deg[i]; }
  if (t == 1023) rowptr[N_NODES] = run;
}

__global__ void fill_csr(const int* __restrict__ ei, const int* __restrict__ rowptr,
                         int* fill, int* __restrict__ csr_src) {
  int e = blockIdx.x * blockDim.x + threadIdx.x;
  if (e >= EPRIME) return;
  int s, d;
  if (e < N_EDGES) { s = ei[e]; d = ei[N_EDGES + e]; }
  else             { s = d = e - N_EDGES; }
  int pos = rowptr[d] + atomicAdd(&fill[d], 1);
  csr_src[pos] = s;
}

// ---------------- node encoder ----------------
__global__ void encode_h(const void* __restrict__ x, const void* __restrict__ Wn,
                         const void* __restrict__ bn, ushort_t* __restrict__ h,
                         const int* __restrict__ dflag) {
  int isf32 = *dflag;
  int tid = blockIdx.x * blockDim.x + threadIdx.x;
  if (tid >= N_NODES * 64) return;
  int n = tid >> 6, j = tid & 63;
  float x0 = ldf(x, n * 3 + 0, isf32), x1 = ldf(x, n * 3 + 1, isf32), x2 = ldf(x, n * 3 + 2, isf32);
  float v = x0 * ldf(Wn, j, isf32) + x1 * ldf(Wn, 64 + j, isf32)
          + x2 * ldf(Wn, 128 + j, isf32) + ldf(bn, j, isf32);
  h[tid] = f2bf(v);
}

// ---------------- MFMA GEMM + fused attn-coef epilogue ------------------------
__global__ __launch_bounds__(256) void gemm_bt(
    const ushort_t* __restrict__ A, const ushort_t* __restrict__ BT,
    ushort_t* __restrict__ C, int K, int ldc,
    const ushort_t* __restrict__ att, float* __restrict__ asrc, float* __restrict__ adst)
{
  __shared__ __align__(16) ushort_t As[128][32];
  __shared__ __align__(16) ushort_t Bs[128][32];
  int tid = threadIdx.x;
  int wave = tid >> 6, lane = tid & 63;
  int wr = wave >> 1, wc = wave & 1;
  int row0 = blockIdx.x * 128, col0 = blockIdx.y * 128;
  int fm = lane & 15, fq = lane >> 4;

  f32x4_t acc[4][4];
  #pragma unroll
  for (int i = 0; i < 4; ++i)
    #pragma unroll
    for (int j = 0; j < 4; ++j) acc[i][j] = (f32x4_t){0.f, 0.f, 0.f, 0.f};

  int srow = wave * 32 + (lane >> 2);
  int skel = (lane & 3) * 8;
  const ushort_t* aG0 = A  + (size_t)(row0 + srow) * K + skel;
  const ushort_t* aG1 = A  + (size_t)(row0 + srow + 16) * K + skel;
  const ushort_t* bG0 = BT + (size_t)(col0 + srow) * K + skel;
  const ushort_t* bG1 = BT + (size_t)(col0 + srow + 16) * K + skel;
  ushort_t* aL0 = &As[wave * 32][0];
  ushort_t* aL1 = &As[wave * 32 + 16][0];
  ushort_t* bL0 = &Bs[wave * 32][0];
  ushort_t* bL1 = &Bs[wave * 32 + 16][0];

  for (int k0 = 0; k0 < K; k0 += 32) {
    gll16(aG0 + k0, aL0);
    gll16(aG1 + k0, aL1);
    gll16(bG0 + k0, bL0);
    gll16(bG1 + k0, bL1);
    __syncthreads();
    bf16x8_t af[4], bfr[4];
    #pragma unroll
    for (int i = 0; i < 4; ++i) af[i]  = *(const bf16x8_t*)&As[64 * wr + 16 * i + fm][fq * 8];
    #pragma unroll
    for (int j = 0; j < 4; ++j) bfr[j] = *(const bf16x8_t*)&Bs[64 * wc + 16 * j + fm][fq * 8];
    #pragma unroll
    for (int i = 0; i < 4; ++i)
      #pragma unroll
      for (int j = 0; j < 4; ++j)
        acc[i][j] = __builtin_amdgcn_mfma_f32_16x16x32_bf16(af[i], bfr[j], acc[i][j], 0, 0, 0);
    __syncthreads();
  }

  int do_att = (att != nullptr);
  int head = 2 * blockIdx.y + wc;
  float sa[4], sd[4];
  if (do_att) {
    #pragma unroll
    for (int j = 0; j < 4; ++j) {
      int ch = 16 * j + fm;
      sa[j] = bf2f(att[head * CH + ch]);
      sd[j] = bf2f(att[512 + head * CH + ch]);
    }
  }

  // C/D layout: col = lane&15, row = (lane>>4)*4 + reg
  #pragma unroll
  for (int i = 0; i < 4; ++i) {
    int rowb = row0 + 64 * wr + 16 * i + fq * 4;
    #pragma unroll
    for (int r = 0; r < 4; ++r) {
      int row = rowb + r;
      float ss = 0.f, dd = 0.f;
      #pragma unroll
      for (int j = 0; j < 4; ++j) {
        ushort_t uv = f2bf(acc[i][j][r]);
        C[(size_t)row * ldc + col0 + 64 * wc + 16 * j + fm] = uv;
        if (do_att) {
          float cv = bf2f(uv);
          ss += cv * sa[j];
          dd += cv * sd[j];
        }
      }
      if (do_att) {
        #pragma unroll
        for (int off = 8; off > 0; off >>= 1) {
          ss += __shfl_down(ss, off);
          dd += __shfl_down(dd, off);
        }
        if (fm == 0 && row < N_NODES) {
          asrc[row * HEADS + head] = ss;
          adst[row * HEADS + head] = dd;
        }
      }
    }
  }
}

// ---------------- aggregation v3: wave-per-edge-subset, packed-f32 FMAs -------
// 4 waves split the edge list (interleaved); each wave covers ALL 512 channels
// (8 ch/lane, one 16B load per edge, 1 exp, 1 asrc gather, scalarized index).
// Accumulation in f32x2 pairs -> v_pk_fma_f32 (half the FMA issue slots).
// sumv stores the RECIPROCAL 1/l (consumed only by edge_head as a multiply).
__global__ __launch_bounds__(256) void aggregate2(
    const int* __restrict__ rowptr, const int* __restrict__ csr_src,
    const float* __restrict__ asrc, const float* __restrict__ adst,
    float* __restrict__ sumv,
    const ushort_t* __restrict__ g,
    const void* __restrict__ x, const void* __restrict__ Wr,
    const void* __restrict__ br, const void* __restrict__ bc,
    ushort_t* __restrict__ out, int mean_mode,
    const void* __restrict__ Wo, const void* __restrict__ bo,
    void* __restrict__ outh, const int* __restrict__ dflag)
{
  int isf32 = *dflag;
  __shared__ float red[4][512];
  __shared__ float lred[4][8];
  __shared__ float sx[3];
  int n = blockIdx.x;
  int t = threadIdx.x;
  int wave = t >> 6, lane = t & 63;
  if (t < 3) sx[t] = ldf(x, n * 3 + t, isf32);

  int ch0 = lane * 8;        // 8 contiguous channels
  int hh  = lane >> 3;       // head owning these channels
  int start = rowptr[n], end = rowptr[n + 1];
  float ad = adst[n * HEADS + hh];

  f32x2_t acc2[4];
  #pragma unroll
  for (int k = 0; k < 4; ++k) acc2[k] = (f32x2_t){0.f, 0.f};
  float l = 0.f;

  int i = start + wave;
  for (; i + 4 < end; i += 8) {           // 2 edges in flight
    int iu0 = __builtin_amdgcn_readfirstlane(i);
    int iu1 = __builtin_amdgcn_readfirstlane(i + 4);
    int s0 = csr_src[iu0];
    int s1 = csr_src[iu1];
    float e0 = asrc[s0 * HEADS + hh] + ad;
    float e1 = asrc[s1 * HEADS + hh] + ad;
    uint4 gv0 = *(const uint4*)(g + (size_t)s0 * FDIM + ch0);
    uint4 gv1 = *(const uint4*)(g + (size_t)s1 * FDIM + ch0);
    float p0 = __expf(leakyf(e0));
    float p1 = __expf(leakyf(e1));
    l += p0 + p1;
    f32x2_t q0 = sp2(p0), q1 = sp2(p1);
    acc2[0] += q0 * bfpair(gv0.x); acc2[0] += q1 * bfpair(gv1.x);
    acc2[1] += q0 * bfpair(gv0.y); acc2[1] += q1 * bfpair(gv1.y);
    acc2[2] += q0 * bfpair(gv0.z); acc2[2] += q1 * bfpair(gv1.z);
    acc2[3] += q0 * bfpair(gv0.w); acc2[3] += q1 * bfpair(gv1.w);
  }
  if (i < end) {
    int iu0 = __builtin_amdgcn_readfirstlane(i);
    int s0 = csr_src[iu0];
    float e0 = asrc[s0 * HEADS + hh] + ad;
    uint4 gv0 = *(const uint4*)(g + (size_t)s0 * FDIM + ch0);
    float p0 = __expf(leakyf(e0));
    l += p0;
    f32x2_t q0 = sp2(p0);
    acc2[0] += q0 * bfpair(gv0.x);
    acc2[1] += q0 * bfpair(gv0.y);
    acc2[2] += q0 * bfpair(gv0.z);
    acc2[3] += q0 * bfpair(gv0.w);
  }

  #pragma unroll
  for (int k = 0; k < 4; ++k) {
    red[wave][ch0 + 2 * k]     = acc2[k][0];
    red[wave][ch0 + 2 * k + 1] = acc2[k][1];
  }
  if ((lane & 7) == 0) lred[wave][hh] = l;
  __syncthreads();

  // combine: thread t covers channels (2t, 2t+1), head t>>5 (old layout)
  int c0 = t * 2;
  int h  = t >> 5;
  float a0 = red[0][c0]     + red[1][c0]     + red[2][c0]     + red[3][c0];
  float a1 = red[0][c0 + 1] + red[1][c0 + 1] + red[2][c0 + 1] + red[3][c0 + 1];
  float lt = lred[0][h] + lred[1][h] + lred[2][h] + lred[3][h];
  a0 /= lt;
  a1 /= lt;
  if ((t & 31) == 0) sumv[n * HEADS + h] = 1.f / lt;   // reciprocal

  if (!mean_mode) {
    float r0 = sx[0] * ldf(Wr, c0, isf32)         + sx[1] * ldf(Wr, 512 + c0, isf32)
             + sx[2] * ldf(Wr, 1024 + c0, isf32)  + ldf(br, c0, isf32);
    float r1 = sx[0] * ldf(Wr, c0 + 1, isf32)     + sx[1] * ldf(Wr, 512 + c0 + 1, isf32)
             + sx[2] * ldf(Wr, 1024 + c0 + 1, isf32) + ldf(br, c0 + 1, isf32);
    unsigned int o0 = f2bf(eluf(a0 + ldf(bc, c0, isf32)) + r0);
    unsigned int o1 = f2bf(eluf(a1 + ldf(bc, c0 + 1, isf32)) + r1);
    *(unsigned int*)(out + (size_t)n * FDIM + c0) = o0 | (o1 << 16);
  } else {
    __syncthreads();                      // red[] reads above must complete
    red[0][c0] = a0; red[0][c0 + 1] = a1;
    __syncthreads();
    if (t < 64) {                               // wave 0, uniform branch
      float tot = 0.f;
      #pragma unroll
      for (int hh2 = 0; hh2 < 8; ++hh2) tot += red[0][t + 64 * hh2];
      ushort_t uv = f2bf(eluf(tot * 0.125f + ldf(bc, t, isf32)));
      out[(size_t)n * CH + t] = uv;
      // fused node head on the bf16-rounded ne value (matches old node_head)
      float nv = bf2f(uv);
      float p0 = nv * ldf(Wo, t * 2 + 0, isf32);
      float p1 = nv * ldf(Wo, t * 2 + 1, isf32);
      float vv = (t & 1) ? p1 : p0;
      float ww = (t & 1) ? p0 : p1;
      vv += __shfl_xor(ww, 1);
      #pragma unroll
      for (int off = 2; off < 64; off <<= 1) vv += __shfl_xor(vv, off);
      if (t < 2) stf(outh, (size_t)n * 2 + t, vv + ldf(bo, t, isf32), isf32);
    }
  }
}

// ---------------- edge head v7: DS-free + packed-f32 channel math -------------
// Same structure as v6 (original edge order, 2-edge pipeline, readlane alpha,
// DPP reduce), but the 4 channels/lane are processed as 2 f32x2 pairs so the
// MLP arithmetic emits v_pk_fma_f32/v_pk_add_f32/v_pk_max_f32 (half the issue
// slots of the scalar form on an 86%-VALUBusy kernel).
#define EPW 32
__global__ __launch_bounds__(256) void edge_head7(
    const int* __restrict__ ei, const float* __restrict__ asrc, const float* __restrict__ adst,
    const float* __restrict__ rsumv,
    const ushort_t* __restrict__ pq, const void* __restrict__ Wm1,
    const void* __restrict__ bm1, const void* __restrict__ Wm2,
    const void* __restrict__ bm2, void* __restrict__ out,
    const int* __restrict__ dflag)
{
  int isf32 = *dflag;
  int lane = threadIdx.x & 63;
  int c0 = lane * 4;
  int h = lane & 7;
  f32x2_t w1r[8][2], w2a[2], w2b[2], b1r[2];
  #pragma unroll
  for (int hh = 0; hh < 8; ++hh)
    #pragma unroll
    for (int jp = 0; jp < 2; ++jp)
      w1r[hh][jp] = (f32x2_t){ ldf(Wm1, (64 + hh) * 256 + c0 + 2 * jp, isf32),
                               ldf(Wm1, (64 + hh) * 256 + c0 + 2 * jp + 1, isf32) };
  #pragma unroll
  for (int jp = 0; jp < 2; ++jp) {
    w2a[jp] = (f32x2_t){ ldf(Wm2, (c0 + 2 * jp) * 2 + 0, isf32),
                         ldf(Wm2, (c0 + 2 * jp + 1) * 2 + 0, isf32) };
    w2b[jp] = (f32x2_t){ ldf(Wm2, (c0 + 2 * jp) * 2 + 1, isf32),
                         ldf(Wm2, (c0 + 2 * jp + 1) * 2 + 1, isf32) };
    b1r[jp] = (f32x2_t){ ldf(bm1, c0 + 2 * jp, isf32),
                         ldf(bm1, c0 + 2 * jp + 1, isf32) };
  }
  float bo0 = ldf(bm2, 0, isf32), bo1 = ldf(bm2, 1, isf32);
  const f32x2_t zero2 = (f32x2_t){0.f, 0.f};

  int wid = blockIdx.x * 4 + (threadIdx.x >> 6);
  int e0 = wid * EPW;                       // EPW*4=128 divides N_EDGES exactly
  for (int e = e0; e < e0 + EPW; e += 2) {
    int eu = __builtin_amdgcn_readfirstlane(e);     // uniform -> s_load of indices
    int sA = ei[eu],     dA = ei[N_EDGES + eu];
    int sB = ei[eu + 1], dB = ei[N_EDGES + eu + 1];
    float vA = asrc[sA * HEADS + h] + adst[dA * HEADS + h];
    float vB = asrc[sB * HEADS + h] + adst[dB * HEADS + h];
    float rsA = rsumv[dA * HEADS + h], rsB = rsumv[dB * HEADS + h];
    uint2 pvA = *(const uint2*)(pq + (size_t)sA * FDIM + c0);
    uint2 qvA = *(const uint2*)(pq + (size_t)dA * FDIM + 256 + c0);
    uint2 pvB = *(const uint2*)(pq + (size_t)sB * FDIM + c0);
    uint2 qvB = *(const uint2*)(pq + (size_t)dB * FDIM + 256 + c0);
    float aA = __expf(leakyf(vA)) * rsA;
    float aB = __expf(leakyf(vB)) * rsB;
    // alpha lives in lanes 0..7 (lane&7 == head); lift to SGPRs via readlane
    float alA[8], alB[8];
    #pragma unroll
    for (int hh = 0; hh < 8; ++hh) {
      alA[hh] = __int_as_float(__builtin_amdgcn_readlane(__float_as_int(aA), hh));
      alB[hh] = __int_as_float(__builtin_amdgcn_readlane(__float_as_int(aB), hh));
    }

    f32x2_t pA2[2] = { bfpair(pvA.x), bfpair(pvA.y) };
    f32x2_t qA2[2] = { bfpair(qvA.x), bfpair(qvA.y) };
    f32x2_t pB2[2] = { bfpair(pvB.x), bfpair(pvB.y) };
    f32x2_t qB2[2] = { bfpair(qvB.x), bfpair(qvB.y) };
    f32x2_t aA0 = zero2, aA1 = zero2, aB0 = zero2, aB1 = zero2;
    #pragma unroll
    for (int jp = 0; jp < 2; ++jp) {
      f32x2_t hvA = pA2[jp] + qA2[jp] + b1r[jp];
      f32x2_t hvB = pB2[jp] + qB2[jp] + b1r[jp];
      #pragma unroll
      for (int hh = 0; hh < 8; ++hh) {
        hvA += sp2(alA[hh]) * w1r[hh][jp];
        hvB += sp2(alB[hh]) * w1r[hh][jp];
      }
      hvA = __builtin_elementwise_max(hvA, zero2);
      hvB = __builtin_elementwise_max(hvB, zero2);
      aA0 += hvA * w2a[jp]; aA1 += hvA * w2b[jp];
      aB0 += hvB * w2a[jp]; aB1 += hvB * w2b[jp];
    }
    float accA0 = aA0[0] + aA0[1];
    float accA1 = aA1[0] + aA1[1];
    float accB0 = aB0[0] + aB0[1];
    float accB1 = aB1[0] + aB1[1];
    accA0 = dpp_sum64(accA0);
    accA1 = dpp_sum64(accA1);
    accB0 = dpp_sum64(accB0);
    accB1 = dpp_sum64(accB1);
    if (lane == 63) {
      stf(out, 100000 + (size_t)e * 2 + 0, accA0 + bo0, isf32);
      stf(out, 100000 + (size_t)e * 2 + 1, accA1 + bo1, isf32);
      stf(out, 100000 + (size_t)e * 2 + 2, accB0 + bo0, isf32);
      stf(out, 100000 + (size_t)e * 2 + 3, accB1 + bo1, isf32);
    }
  }
}

// ---------------- launch ----------------
extern "C" void kernel_launch(void* const* d_in, const int* in_sizes, int n_in,
                              void* d_out, int out_size, void* d_ws, size_t ws_size,
                              hipStream_t stream) {
  const void* x   = d_in[0];
  const int*  ei  = (const int*)d_in[1];
  const void* Wn  = d_in[4];
  const void* bn  = d_in[5];
  const void* Wr  = d_in[6];
  const void* br  = d_in[7];
  const void* W1  = d_in[8];
  const void* as1 = d_in[9];
  const void* ad1 = d_in[10];
  const void* bc1 = d_in[11];
  const void* W2  = d_in[12];
  const void* as2 = d_in[13];
  const void* ad2 = d_in[14];
  const void* bc2 = d_in[15];
  const void* W3  = d_in[16];
  const void* as3 = d_in[17];
  const void* ad3 = d_in[18];
  const void* bc3 = d_in[19];
  const void* Wo  = d_in[20];
  const void* bo  = d_in[21];
  const void* Wm1 = d_in[22];
  const void* bm1 = d_in[23];
  const void* Wm2 = d_in[24];
  const void* bm2 = d_in[25];

  char* ws = (char*)d_ws;
  size_t off = 0;
  auto take = [&](size_t bytes) -> char* {
    char* p = ws + off;
    off += (bytes + 255) & ~(size_t)255;
    return p;
  };
  ushort_t* h_bf   = (ushort_t*)take((size_t)NPAD * 64 * 2);       // enc out / node_embedding
  ushort_t* g_bf   = (ushort_t*)take((size_t)NPAD * FDIM * 2);     // gemm out / P|Q
  ushort_t* o_bf   = (ushort_t*)take((size_t)NPAD * FDIM * 2);     // layer out
  float*    asrc   = (float*)take((size_t)N_NODES * HEADS * 4);
  float*    adst   = (float*)take((size_t)N_NODES * HEADS * 4);
  float*    sumv   = (float*)take((size_t)N_NODES * HEADS * 4);
  int*      rowptr = (int*)take((size_t)(N_NODES + 1) * 4);
  int*      csr_src= (int*)take((size_t)EPRIME * 4);
  int*      deg    = (int*)take((size_t)N_NODES * 4);
  int*      fillc  = (int*)take((size_t)N_NODES * 4);
  int*      dflag  = (int*)take(256);
  ushort_t* WT1    = (ushort_t*)take((size_t)512 * 64 * 2);        // W1^T  [512][64]
  ushort_t* WT2    = (ushort_t*)take((size_t)512 * 512 * 2);       // W2^T  [512][512]
  ushort_t* WT3    = (ushort_t*)take((size_t)512 * 512 * 2);       // W3^T  [512][512]
  ushort_t* WTPQ   = (ushort_t*)take((size_t)512 * 64 * 2);        // [P^T ; Q^T] combined
  ushort_t* attv   = (ushort_t*)take((size_t)6 * 512 * 2);         // packed a_src/a_dst x3

  dim3 b256(256);
  const int MB = NPAD / 128;  // 391

  detect_dtype<<<dim3(1), dim3(64), 0, stream>>>(Wn, dflag);

  // weight conversion (transpose to [n][k], bf16); W1 is [64,512] -> K=64
  convert_wt<<<dim3(128),  b256, 0, stream>>>(W1, WT1, 64, 512, 0, dflag);
  convert_wt<<<dim3(1024), b256, 0, stream>>>(W2, WT2, 512, 512, 0, dflag);
  convert_wt<<<dim3(1024), b256, 0, stream>>>(W3, WT3, 512, 512, 0, dflag);
  convert_wt<<<dim3(64),   b256, 0, stream>>>(Wm1, WTPQ,            64, 256, 0,  dflag);
  convert_wt<<<dim3(64),   b256, 0, stream>>>(Wm1, WTPQ + 256 * 64, 64, 256, 72, dflag);
  convert_att<<<dim3(12),  b256, 0, stream>>>(as1, ad1, as2, ad2, as3, ad3, attv, dflag);

  // CSR build
  init_deg<<<dim3((N_NODES + 255) / 256), b256, 0, stream>>>(deg, fillc);
  count_edges<<<dim3((N_EDGES + 255) / 256), b256, 0, stream>>>(ei, deg);
  scan1024<<<dim3(1), dim3(1024), 0, stream>>>(deg, rowptr);
  fill_csr<<<dim3((EPRIME + 255) / 256), b256, 0, stream>>>(ei, rowptr, fillc, csr_src);

  // node encoder
  encode_h<<<dim3((N_NODES * 64 + 255) / 256), b256, 0, stream>>>(x, Wn, bn, h_bf, dflag);

  // ---- GAT layer 1 (in: h_bf [NPAD,64]); attn fused in gemm epilogue ----
  gemm_bt<<<dim3(MB, 4), b256, 0, stream>>>(h_bf, WT1, g_bf, 64, 512,
                                            attv, asrc, adst);
  aggregate2<<<dim3(N_NODES), b256, 0, stream>>>(rowptr, csr_src, asrc, adst, sumv,
                                                 g_bf, x, Wr, br, bc1, o_bf, 0,
                                                 nullptr, nullptr, d_out, dflag);

  // ---- GAT layer 2 ----
  gemm_bt<<<dim3(MB, 4), b256, 0, stream>>>(o_bf, WT2, g_bf, 512, 512,
                                            attv + 1024, asrc, adst);
  aggregate2<<<dim3(N_NODES), b256, 0, stream>>>(rowptr, csr_src, asrc, adst, sumv,
                                                 g_bf, x, Wr, br, bc2, o_bf, 0,
                                                 nullptr, nullptr, d_out, dflag);

  // ---- GAT layer 3 (mean over heads -> ne in h_bf; node head fused) ----
  gemm_bt<<<dim3(MB, 4), b256, 0, stream>>>(o_bf, WT3, g_bf, 512, 512,
                                            attv + 2048, asrc, adst);
  aggregate2<<<dim3(N_NODES), b256, 0, stream>>>(rowptr, csr_src, asrc, adst, sumv,
                                                 g_bf, x, Wr, br, bc3, h_bf, 1,
                                                 Wo, bo, d_out, dflag);

  // ---- edge head: P|Q in one gemm, then per-edge MLP (DS-free, packed) ----
  gemm_bt<<<dim3(MB, 4), b256, 0, stream>>>(h_bf, WTPQ, g_bf, 64, 512,
                                            nullptr, nullptr, nullptr);
  edge_head7<<<dim3(N_EDGES / (EPW * 4)), b256, 0, stream>>>(ei, asrc, adst, sumv, g_bf,
                                                             Wm1, bm1, Wm2, bm2,
                                                             d_out, dflag);
}

// Round 7
// 1015.560 us; speedup vs baseline: 1.2994x; 1.0056x over previous
//
#include <hip/hip_runtime.h>
#include <hip/hip_bf16.h>
#include <math.h>

#define N_NODES 50000
#define NPAD    50048                  // N_NODES rounded up to 128 (gemm tiles, no guards)
#define N_EDGES 800000
#define EPRIME  (N_EDGES + N_NODES)   // edges + self loops
#define HEADS 8
#define CH 64
#define FDIM 512                       // HEADS*CH

typedef unsigned short ushort_t;
typedef __attribute__((ext_vector_type(8))) short bf16x8_t;  // 8 bf16 = 4 VGPRs
typedef __attribute__((ext_vector_type(4))) float f32x4_t;
typedef __attribute__((ext_vector_type(2))) float f32x2_t;   // packed fp32 (v_pk_*)

__device__ __forceinline__ float bf2f(unsigned short u) {
  union { unsigned int i; float f; } v; v.i = ((unsigned int)u) << 16; return v.f;
}
__device__ __forceinline__ unsigned short f2bf(float f) {
  union { float f; unsigned int i; } v; v.f = f;
  unsigned int x = v.i;
  return (unsigned short)((x + 0x7fffu + ((x >> 16) & 1u)) >> 16);  // RNE
}
__device__ __forceinline__ float ldf(const void* p, size_t idx, int isf32) {
  return isf32 ? ((const float*)p)[idx] : bf2f(((const ushort_t*)p)[idx]);
}
__device__ __forceinline__ void stf(void* p, size_t idx, float v, int isf32) {
  if (isf32) ((float*)p)[idx] = v;
  else       ((ushort_t*)p)[idx] = f2bf(v);
}
__device__ __forceinline__ float leakyf(float v) { return v >= 0.f ? v : 0.2f * v; }
__device__ __forceinline__ float eluf(float v)   { return v > 0.f ? v : expm1f(v); }

__device__ __forceinline__ f32x2_t sp2(float s) { return (f32x2_t){s, s}; }
// unpack a u32 holding two bf16 (lo = even channel, hi = odd channel) to f32x2
__device__ __forceinline__ f32x2_t bfpair(unsigned int u) {
  union { unsigned int i; float f; } lo, hi;
  lo.i = u << 16; hi.i = u & 0xffff0000u;
  return (f32x2_t){lo.f, hi.f};
}

// wave64 sum via DPP butterfly (LLVM AtomicOptimizer sequence); full sum valid
// in lanes 48..63 (use lane 63). Pure VALU — no DS pipe, no LDS.
__device__ __forceinline__ float dpp_sum64(float x) {
  x += __int_as_float(__builtin_amdgcn_update_dpp(0, __float_as_int(x), 0xB1, 0xf, 0xf, false)); // quad_perm [1,0,3,2]
  x += __int_as_float(__builtin_amdgcn_update_dpp(0, __float_as_int(x), 0x4E, 0xf, 0xf, false)); // quad_perm [2,3,0,1]
  x += __int_as_float(__builtin_amdgcn_update_dpp(0, __float_as_int(x), 0x141, 0xf, 0xf, false)); // row_half_mirror
  x += __int_as_float(__builtin_amdgcn_update_dpp(0, __float_as_int(x), 0x140, 0xf, 0xf, false)); // row_mirror
  x += __int_as_float(__builtin_amdgcn_update_dpp(0, __float_as_int(x), 0x142, 0xa, 0xf, false)); // row_bcast:15 rows 1,3
  x += __int_as_float(__builtin_amdgcn_update_dpp(0, __float_as_int(x), 0x143, 0xc, 0xf, false)); // row_bcast:31 rows 2,3
  return x;
}

// async global->LDS, 16B per lane; LDS dest = wave-uniform base + lane*16
typedef const __attribute__((address_space(1))) unsigned int* gas1_t;
typedef __attribute__((address_space(3))) unsigned int* las3_t;
__device__ __forceinline__ void gll16(const ushort_t* g, ushort_t* l) {
  __builtin_amdgcn_global_load_lds((gas1_t)g, (las3_t)l, 16, 0, 0);
}

// ---------------- dtype detector (wave-parallel) ----------------
__global__ void detect_dtype(const void* Wn, int* flag) {
  const ushort_t* u = (const ushort_t*)Wn;
  int lane = threadIdx.x;
  int cnt = 0;
  for (int i = lane; i < 384; i += 64) {
    float v = fabsf(bf2f(u[i]));
    if (v != 0.f && (v > 16.f || v < 6.1e-5f)) cnt++;
  }
  #pragma unroll
  for (int off = 32; off > 0; off >>= 1) cnt += __shfl_down(cnt, off);
  if (lane == 0) *flag = (cnt >= 20) ? 1 : 0;
}

// ---------------- weight transpose-convert, LDS-tiled (coalesced both sides) --
// dst[n*K+k] = src[(boff+k)*N + n]; requires K,N multiples of 32.
__global__ __launch_bounds__(256) void convert_wt_t(const void* __restrict__ src,
                                                    ushort_t* __restrict__ dst,
                                                    int K, int N, int boff,
                                                    const int* __restrict__ dflag) {
  int isf32 = *dflag;
  __shared__ float tile[32][33];
  int n0 = blockIdx.x * 32, k0 = blockIdx.y * 32;
  int tx = threadIdx.x & 31, ty = threadIdx.x >> 5;   // 32 x 8
  #pragma unroll
  for (int r = 0; r < 4; ++r)
    tile[ty + 8 * r][tx] = ldf(src, (size_t)(boff + k0 + ty + 8 * r) * N + n0 + tx, isf32);
  __syncthreads();
  #pragma unroll
  for (int r = 0; r < 4; ++r)
    dst[(size_t)(n0 + ty + 8 * r) * K + k0 + tx] = f2bf(tile[tx][ty + 8 * r]);
}

// pack 6 attention vectors (3 layers x {a_src, a_dst}, 512 elems each) to bf16
__global__ void convert_att(const void* s1, const void* d1, const void* s2, const void* d2,
                            const void* s3, const void* d3, ushort_t* __restrict__ dst,
                            const int* __restrict__ dflag) {
  int isf32 = *dflag;
  int tid = blockIdx.x * blockDim.x + threadIdx.x;
  if (tid >= 6 * 512) return;
  int which = tid >> 9, idx = tid & 511;
  const void* p = which == 0 ? s1 : which == 1 ? d1 : which == 2 ? s2
                : which == 3 ? d2 : which == 4 ? s3 : d3;
  dst[tid] = f2bf(ldf(p, idx, isf32));
}

// ---------------- CSR build ----------------
__global__ void init_deg(int* deg, int* fill) {
  int n = blockIdx.x * blockDim.x + threadIdx.x;
  if (n < N_NODES) { deg[n] = 1; fill[n] = 0; }   // 1 = self loop
}

__global__ void count_edges(const int* __restrict__ ei, int* deg) {
  int e = blockIdx.x * blockDim.x + threadIdx.x;
  if (e < N_EDGES) atomicAdd(&deg[ei[N_EDGES + e]], 1);
}

// parallel exclusive scan of deg[0..N_NODES) -> rowptr; 1 block x 1024 threads.
__global__ __launch_bounds__(1024) void scan1024(const int* __restrict__ deg,
                                                 int* __restrict__ rowptr) {
  const int CHUNK = (N_NODES + 1023) / 1024;   // 49
  int t = threadIdx.x;
  int wave = t >> 6, lane = t & 63;
  int lo = t * CHUNK;
  int hi = lo + CHUNK; if (hi > N_NODES) hi = N_NODES;
  int s = 0;
  for (int i = lo; i < hi; ++i) s += deg[i];
  int inc = s;
  #pragma unroll
  for (int off = 1; off < 64; off <<= 1) {
    int u = __shfl_up(inc, off);
    if (lane >= off) inc += u;
  }
  __shared__ int wsum[16];
  if (lane == 63) wsum[wave] = inc;
  __syncthreads();
  int wbase = 0;
  for (int w = 0; w < wave; ++w) wbase += wsum[w];
  int run = wbase + inc - s;                   // exclusive prefix for this thread
  for (int i = lo; i < hi; ++i) { rowptr[i] = run; run += deg[i]; }
  if (t == 1023) rowptr[N_NODES] = run;
}

__global__ void fill_csr(const int* __restrict__ ei, const int* __restrict__ rowptr,
                         int* fill, int* __restrict__ csr_src) {
  int e = blockIdx.x * blockDim.x + threadIdx.x;
  if (e >= EPRIME) return;
  int s, d;
  if (e < N_EDGES) { s = ei[e]; d = ei[N_EDGES + e]; }
  else             { s = d = e - N_EDGES; }
  int pos = rowptr[d] + atomicAdd(&fill[d], 1);
  csr_src[pos] = s;
}

// ---------------- node encoder ----------------
__global__ void encode_h(const void* __restrict__ x, const void* __restrict__ Wn,
                         const void* __restrict__ bn, ushort_t* __restrict__ h,
                         const int* __restrict__ dflag) {
  int isf32 = *dflag;
  int tid = blockIdx.x * blockDim.x + threadIdx.x;
  if (tid >= N_NODES * 64) return;
  int n = tid >> 6, j = tid & 63;
  float x0 = ldf(x, n * 3 + 0, isf32), x1 = ldf(x, n * 3 + 1, isf32), x2 = ldf(x, n * 3 + 2, isf32);
  float v = x0 * ldf(Wn, j, isf32) + x1 * ldf(Wn, 64 + j, isf32)
          + x2 * ldf(Wn, 128 + j, isf32) + ldf(bn, j, isf32);
  h[tid] = f2bf(v);
}

// ---------------- MFMA GEMM + fused attn-coef epilogue ------------------------
__global__ __launch_bounds__(256) void gemm_bt(
    const ushort_t* __restrict__ A, const ushort_t* __restrict__ BT,
    ushort_t* __restrict__ C, int K, int ldc,
    const ushort_t* __restrict__ att, float* __restrict__ asrc, float* __restrict__ adst)
{
  __shared__ __align__(16) ushort_t As[128][32];
  __shared__ __align__(16) ushort_t Bs[128][32];
  int tid = threadIdx.x;
  int wave = tid >> 6, lane = tid & 63;
  int wr = wave >> 1, wc = wave & 1;
  int row0 = blockIdx.x * 128, col0 = blockIdx.y * 128;
  int fm = lane & 15, fq = lane >> 4;

  f32x4_t acc[4][4];
  #pragma unroll
  for (int i = 0; i < 4; ++i)
    #pragma unroll
    for (int j = 0; j < 4; ++j) acc[i][j] = (f32x4_t){0.f, 0.f, 0.f, 0.f};

  int srow = wave * 32 + (lane >> 2);
  int skel = (lane & 3) * 8;
  const ushort_t* aG0 = A  + (size_t)(row0 + srow) * K + skel;
  const ushort_t* aG1 = A  + (size_t)(row0 + srow + 16) * K + skel;
  const ushort_t* bG0 = BT + (size_t)(col0 + srow) * K + skel;
  const ushort_t* bG1 = BT + (size_t)(col0 + srow + 16) * K + skel;
  ushort_t* aL0 = &As[wave * 32][0];
  ushort_t* aL1 = &As[wave * 32 + 16][0];
  ushort_t* bL0 = &Bs[wave * 32][0];
  ushort_t* bL1 = &Bs[wave * 32 + 16][0];

  for (int k0 = 0; k0 < K; k0 += 32) {
    gll16(aG0 + k0, aL0);
    gll16(aG1 + k0, aL1);
    gll16(bG0 + k0, bL0);
    gll16(bG1 + k0, bL1);
    __syncthreads();
    bf16x8_t af[4], bfr[4];
    #pragma unroll
    for (int i = 0; i < 4; ++i) af[i]  = *(const bf16x8_t*)&As[64 * wr + 16 * i + fm][fq * 8];
    #pragma unroll
    for (int j = 0; j < 4; ++j) bfr[j] = *(const bf16x8_t*)&Bs[64 * wc + 16 * j + fm][fq * 8];
    #pragma unroll
    for (int i = 0; i < 4; ++i)
      #pragma unroll
      for (int j = 0; j < 4; ++j)
        acc[i][j] = __builtin_amdgcn_mfma_f32_16x16x32_bf16(af[i], bfr[j], acc[i][j], 0, 0, 0);
    __syncthreads();
  }

  int do_att = (att != nullptr);
  int head = 2 * blockIdx.y + wc;
  float sa[4], sd[4];
  if (do_att) {
    #pragma unroll
    for (int j = 0; j < 4; ++j) {
      int ch = 16 * j + fm;
      sa[j] = bf2f(att[head * CH + ch]);
      sd[j] = bf2f(att[512 + head * CH + ch]);
    }
  }

  // C/D layout: col = lane&15, row = (lane>>4)*4 + reg
  #pragma unroll
  for (int i = 0; i < 4; ++i) {
    int rowb = row0 + 64 * wr + 16 * i + fq * 4;
    #pragma unroll
    for (int r = 0; r < 4; ++r) {
      int row = rowb + r;
      float ss = 0.f, dd = 0.f;
      #pragma unroll
      for (int j = 0; j < 4; ++j) {
        ushort_t uv = f2bf(acc[i][j][r]);
        C[(size_t)row * ldc + col0 + 64 * wc + 16 * j + fm] = uv;
        if (do_att) {
          float cv = bf2f(uv);
          ss += cv * sa[j];
          dd += cv * sd[j];
        }
      }
      if (do_att) {
        #pragma unroll
        for (int off = 8; off > 0; off >>= 1) {
          ss += __shfl_down(ss, off);
          dd += __shfl_down(dd, off);
        }
        if (fm == 0 && row < N_NODES) {
          asrc[row * HEADS + head] = ss;
          adst[row * HEADS + head] = dd;
        }
      }
    }
  }
}

// ---------------- aggregation v3: wave-per-edge-subset, packed-f32 FMAs -------
__global__ __launch_bounds__(256) void aggregate2(
    const int* __restrict__ rowptr, const int* __restrict__ csr_src,
    const float* __restrict__ asrc, const float* __restrict__ adst,
    float* __restrict__ sumv,
    const ushort_t* __restrict__ g,
    const void* __restrict__ x, const void* __restrict__ Wr,
    const void* __restrict__ br, const void* __restrict__ bc,
    ushort_t* __restrict__ out, int mean_mode,
    const void* __restrict__ Wo, const void* __restrict__ bo,
    void* __restrict__ outh, const int* __restrict__ dflag)
{
  int isf32 = *dflag;
  __shared__ float red[4][512];
  __shared__ float lred[4][8];
  __shared__ float sx[3];
  int n = blockIdx.x;
  int t = threadIdx.x;
  int wave = t >> 6, lane = t & 63;
  if (t < 3) sx[t] = ldf(x, n * 3 + t, isf32);

  int ch0 = lane * 8;        // 8 contiguous channels
  int hh  = lane >> 3;       // head owning these channels
  int start = rowptr[n], end = rowptr[n + 1];
  float ad = adst[n * HEADS + hh];

  f32x2_t acc2[4];
  #pragma unroll
  for (int k = 0; k < 4; ++k) acc2[k] = (f32x2_t){0.f, 0.f};
  float l = 0.f;

  int i = start + wave;
  for (; i + 4 < end; i += 8) {           // 2 edges in flight
    int iu0 = __builtin_amdgcn_readfirstlane(i);
    int iu1 = __builtin_amdgcn_readfirstlane(i + 4);
    int s0 = csr_src[iu0];
    int s1 = csr_src[iu1];
    float e0 = asrc[s0 * HEADS + hh] + ad;
    float e1 = asrc[s1 * HEADS + hh] + ad;
    uint4 gv0 = *(const uint4*)(g + (size_t)s0 * FDIM + ch0);
    uint4 gv1 = *(const uint4*)(g + (size_t)s1 * FDIM + ch0);
    float p0 = __expf(leakyf(e0));
    float p1 = __expf(leakyf(e1));
    l += p0 + p1;
    f32x2_t q0 = sp2(p0), q1 = sp2(p1);
    acc2[0] += q0 * bfpair(gv0.x); acc2[0] += q1 * bfpair(gv1.x);
    acc2[1] += q0 * bfpair(gv0.y); acc2[1] += q1 * bfpair(gv1.y);
    acc2[2] += q0 * bfpair(gv0.z); acc2[2] += q1 * bfpair(gv1.z);
    acc2[3] += q0 * bfpair(gv0.w); acc2[3] += q1 * bfpair(gv1.w);
  }
  if (i < end) {
    int iu0 = __builtin_amdgcn_readfirstlane(i);
    int s0 = csr_src[iu0];
    float e0 = asrc[s0 * HEADS + hh] + ad;
    uint4 gv0 = *(const uint4*)(g + (size_t)s0 * FDIM + ch0);
    float p0 = __expf(leakyf(e0));
    l += p0;
    f32x2_t q0 = sp2(p0);
    acc2[0] += q0 * bfpair(gv0.x);
    acc2[1] += q0 * bfpair(gv0.y);
    acc2[2] += q0 * bfpair(gv0.z);
    acc2[3] += q0 * bfpair(gv0.w);
  }

  #pragma unroll
  for (int k = 0; k < 4; ++k) {
    red[wave][ch0 + 2 * k]     = acc2[k][0];
    red[wave][ch0 + 2 * k + 1] = acc2[k][1];
  }
  if ((lane & 7) == 0) lred[wave][hh] = l;
  __syncthreads();

  // combine: thread t covers channels (2t, 2t+1), head t>>5 (old layout)
  int c0 = t * 2;
  int h  = t >> 5;
  float a0 = red[0][c0]     + red[1][c0]     + red[2][c0]     + red[3][c0];
  float a1 = red[0][c0 + 1] + red[1][c0 + 1] + red[2][c0 + 1] + red[3][c0 + 1];
  float lt = lred[0][h] + lred[1][h] + lred[2][h] + lred[3][h];
  a0 /= lt;
  a1 /= lt;
  if ((t & 31) == 0) sumv[n * HEADS + h] = 1.f / lt;   // reciprocal

  if (!mean_mode) {
    float r0 = sx[0] * ldf(Wr, c0, isf32)         + sx[1] * ldf(Wr, 512 + c0, isf32)
             + sx[2] * ldf(Wr, 1024 + c0, isf32)  + ldf(br, c0, isf32);
    float r1 = sx[0] * ldf(Wr, c0 + 1, isf32)     + sx[1] * ldf(Wr, 512 + c0 + 1, isf32)
             + sx[2] * ldf(Wr, 1024 + c0 + 1, isf32) + ldf(br, c0 + 1, isf32);
    unsigned int o0 = f2bf(eluf(a0 + ldf(bc, c0, isf32)) + r0);
    unsigned int o1 = f2bf(eluf(a1 + ldf(bc, c0 + 1, isf32)) + r1);
    *(unsigned int*)(out + (size_t)n * FDIM + c0) = o0 | (o1 << 16);
  } else {
    __syncthreads();                      // red[] reads above must complete
    red[0][c0] = a0; red[0][c0 + 1] = a1;
    __syncthreads();
    if (t < 64) {                               // wave 0, uniform branch
      float tot = 0.f;
      #pragma unroll
      for (int hh2 = 0; hh2 < 8; ++hh2) tot += red[0][t + 64 * hh2];
      ushort_t uv = f2bf(eluf(tot * 0.125f + ldf(bc, t, isf32)));
      out[(size_t)n * CH + t] = uv;
      // fused node head on the bf16-rounded ne value (matches old node_head)
      float nv = bf2f(uv);
      float p0 = nv * ldf(Wo, t * 2 + 0, isf32);
      float p1 = nv * ldf(Wo, t * 2 + 1, isf32);
      float vv = (t & 1) ? p1 : p0;
      float ww = (t & 1) ? p0 : p1;
      vv += __shfl_xor(ww, 1);
      #pragma unroll
      for (int off = 2; off < 64; off <<= 1) vv += __shfl_xor(vv, off);
      if (t < 2) stf(outh, (size_t)n * 2 + t, vv + ldf(bo, t, isf32), isf32);
    }
  }
}

// ---------------- edge head v8: packed math + 2-stage load pipeline -----------
// Same math as v7; loads for pair k+1 are issued before computing pair k so
// gather latency hides under the ~70-op MLP block (v7's VALUBusy fell to 75%
// after packing halved the op count — latency became visible).
#define EPW 32
__global__ __launch_bounds__(256) void edge_head8(
    const int* __restrict__ ei, const float* __restrict__ asrc, const float* __restrict__ adst,
    const float* __restrict__ rsumv,
    const ushort_t* __restrict__ pq, const void* __restrict__ Wm1,
    const void* __restrict__ bm1, const void* __restrict__ Wm2,
    const void* __restrict__ bm2, void* __restrict__ out,
    const int* __restrict__ dflag)
{
  int isf32 = *dflag;
  int lane = threadIdx.x & 63;
  int c0 = lane * 4;
  int h = lane & 7;
  f32x2_t w1r[8][2], w2a[2], w2b[2], b1r[2];
  #pragma unroll
  for (int hh = 0; hh < 8; ++hh)
    #pragma unroll
    for (int jp = 0; jp < 2; ++jp)
      w1r[hh][jp] = (f32x2_t){ ldf(Wm1, (64 + hh) * 256 + c0 + 2 * jp, isf32),
                               ldf(Wm1, (64 + hh) * 256 + c0 + 2 * jp + 1, isf32) };
  #pragma unroll
  for (int jp = 0; jp < 2; ++jp) {
    w2a[jp] = (f32x2_t){ ldf(Wm2, (c0 + 2 * jp) * 2 + 0, isf32),
                         ldf(Wm2, (c0 + 2 * jp + 1) * 2 + 0, isf32) };
    w2b[jp] = (f32x2_t){ ldf(Wm2, (c0 + 2 * jp) * 2 + 1, isf32),
                         ldf(Wm2, (c0 + 2 * jp + 1) * 2 + 1, isf32) };
    b1r[jp] = (f32x2_t){ ldf(bm1, c0 + 2 * jp, isf32),
                         ldf(bm1, c0 + 2 * jp + 1, isf32) };
  }
  float bo0 = ldf(bm2, 0, isf32), bo1 = ldf(bm2, 1, isf32);
  const f32x2_t zero2 = (f32x2_t){0.f, 0.f};

  int wid = blockIdx.x * 4 + (threadIdx.x >> 6);
  int e0 = wid * EPW;                       // EPW*4=128 divides N_EDGES exactly

  // pipeline registers (current pair)
  float vA, vB, rsA, rsB;
  uint2 pvA, qvA, pvB, qvB;
  {   // prologue: load pair e0
    int eu = __builtin_amdgcn_readfirstlane(e0);
    int sA = ei[eu],     dA = ei[N_EDGES + eu];
    int sB = ei[eu + 1], dB = ei[N_EDGES + eu + 1];
    vA = asrc[sA * HEADS + h] + adst[dA * HEADS + h];
    vB = asrc[sB * HEADS + h] + adst[dB * HEADS + h];
    rsA = rsumv[dA * HEADS + h]; rsB = rsumv[dB * HEADS + h];
    pvA = *(const uint2*)(pq + (size_t)sA * FDIM + c0);
    qvA = *(const uint2*)(pq + (size_t)dA * FDIM + 256 + c0);
    pvB = *(const uint2*)(pq + (size_t)sB * FDIM + c0);
    qvB = *(const uint2*)(pq + (size_t)dB * FDIM + 256 + c0);
  }

  #pragma unroll
  for (int it = 0; it < EPW / 2; ++it) {
    int e = e0 + 2 * it;
    // snapshot current pair
    float cvA = vA, cvB = vB, crsA = rsA, crsB = rsB;
    uint2 cpvA = pvA, cqvA = qvA, cpvB = pvB, cqvB = qvB;
    // issue next pair's loads (overlaps with compute below)
    if (it + 1 < EPW / 2) {
      int eu = __builtin_amdgcn_readfirstlane(e + 2);
      int sA = ei[eu],     dA = ei[N_EDGES + eu];
      int sB = ei[eu + 1], dB = ei[N_EDGES + eu + 1];
      vA = asrc[sA * HEADS + h] + adst[dA * HEADS + h];
      vB = asrc[sB * HEADS + h] + adst[dB * HEADS + h];
      rsA = rsumv[dA * HEADS + h]; rsB = rsumv[dB * HEADS + h];
      pvA = *(const uint2*)(pq + (size_t)sA * FDIM + c0);
      qvA = *(const uint2*)(pq + (size_t)dA * FDIM + 256 + c0);
      pvB = *(const uint2*)(pq + (size_t)sB * FDIM + c0);
      qvB = *(const uint2*)(pq + (size_t)dB * FDIM + 256 + c0);
    }

    float aA = __expf(leakyf(cvA)) * crsA;
    float aB = __expf(leakyf(cvB)) * crsB;
    // alpha lives in lanes 0..7 (lane&7 == head); lift to SGPRs via readlane
    float alA[8], alB[8];
    #pragma unroll
    for (int hh = 0; hh < 8; ++hh) {
      alA[hh] = __int_as_float(__builtin_amdgcn_readlane(__float_as_int(aA), hh));
      alB[hh] = __int_as_float(__builtin_amdgcn_readlane(__float_as_int(aB), hh));
    }

    f32x2_t pA2[2] = { bfpair(cpvA.x), bfpair(cpvA.y) };
    f32x2_t qA2[2] = { bfpair(cqvA.x), bfpair(cqvA.y) };
    f32x2_t pB2[2] = { bfpair(cpvB.x), bfpair(cpvB.y) };
    f32x2_t qB2[2] = { bfpair(cqvB.x), bfpair(cqvB.y) };
    f32x2_t aA0 = zero2, aA1 = zero2, aB0 = zero2, aB1 = zero2;
    #pragma unroll
    for (int jp = 0; jp < 2; ++jp) {
      f32x2_t hvA = pA2[jp] + qA2[jp] + b1r[jp];
      f32x2_t hvB = pB2[jp] + qB2[jp] + b1r[jp];
      #pragma unroll
      for (int hh = 0; hh < 8; ++hh) {
        hvA += sp2(alA[hh]) * w1r[hh][jp];
        hvB += sp2(alB[hh]) * w1r[hh][jp];
      }
      hvA = __builtin_elementwise_max(hvA, zero2);
      hvB = __builtin_elementwise_max(hvB, zero2);
      aA0 += hvA * w2a[jp]; aA1 += hvA * w2b[jp];
      aB0 += hvB * w2a[jp]; aB1 += hvB * w2b[jp];
    }
    float accA0 = aA0[0] + aA0[1];
    float accA1 = aA1[0] + aA1[1];
    float accB0 = aB0[0] + aB0[1];
    float accB1 = aB1[0] + aB1[1];
    accA0 = dpp_sum64(accA0);
    accA1 = dpp_sum64(accA1);
    accB0 = dpp_sum64(accB0);
    accB1 = dpp_sum64(accB1);
    if (lane == 63) {
      stf(out, 100000 + (size_t)e * 2 + 0, accA0 + bo0, isf32);
      stf(out, 100000 + (size_t)e * 2 + 1, accA1 + bo1, isf32);
      stf(out, 100000 + (size_t)e * 2 + 2, accB0 + bo0, isf32);
      stf(out, 100000 + (size_t)e * 2 + 3, accB1 + bo1, isf32);
    }
  }
}

// ---------------- launch ----------------
extern "C" void kernel_launch(void* const* d_in, const int* in_sizes, int n_in,
                              void* d_out, int out_size, void* d_ws, size_t ws_size,
                              hipStream_t stream) {
  const void* x   = d_in[0];
  const int*  ei  = (const int*)d_in[1];
  const void* Wn  = d_in[4];
  const void* bn  = d_in[5];
  const void* Wr  = d_in[6];
  const void* br  = d_in[7];
  const void* W1  = d_in[8];
  const void* as1 = d_in[9];
  const void* ad1 = d_in[10];
  const void* bc1 = d_in[11];
  const void* W2  = d_in[12];
  const void* as2 = d_in[13];
  const void* ad2 = d_in[14];
  const void* bc2 = d_in[15];
  const void* W3  = d_in[16];
  const void* as3 = d_in[17];
  const void* ad3 = d_in[18];
  const void* bc3 = d_in[19];
  const void* Wo  = d_in[20];
  const void* bo  = d_in[21];
  const void* Wm1 = d_in[22];
  const void* bm1 = d_in[23];
  const void* Wm2 = d_in[24];
  const void* bm2 = d_in[25];

  char* ws = (char*)d_ws;
  size_t off = 0;
  auto take = [&](size_t bytes) -> char* {
    char* p = ws + off;
    off += (bytes + 255) & ~(size_t)255;
    return p;
  };
  ushort_t* h_bf   = (ushort_t*)take((size_t)NPAD * 64 * 2);       // enc out / node_embedding
  ushort_t* g_bf   = (ushort_t*)take((size_t)NPAD * FDIM * 2);     // gemm out / P|Q
  ushort_t* o_bf   = (ushort_t*)take((size_t)NPAD * FDIM * 2);     // layer out
  float*    asrc   = (float*)take((size_t)N_NODES * HEADS * 4);
  float*    adst   = (float*)take((size_t)N_NODES * HEADS * 4);
  float*    sumv   = (float*)take((size_t)N_NODES * HEADS * 4);
  int*      rowptr = (int*)take((size_t)(N_NODES + 1) * 4);
  int*      csr_src= (int*)take((size_t)EPRIME * 4);
  int*      deg    = (int*)take((size_t)N_NODES * 4);
  int*      fillc  = (int*)take((size_t)N_NODES * 4);
  int*      dflag  = (int*)take(256);
  ushort_t* WT1    = (ushort_t*)take((size_t)512 * 64 * 2);        // W1^T  [512][64]
  ushort_t* WT2    = (ushort_t*)take((size_t)512 * 512 * 2);       // W2^T  [512][512]
  ushort_t* WT3    = (ushort_t*)take((size_t)512 * 512 * 2);       // W3^T  [512][512]
  ushort_t* WTPQ   = (ushort_t*)take((size_t)512 * 64 * 2);        // [P^T ; Q^T] combined
  ushort_t* attv   = (ushort_t*)take((size_t)6 * 512 * 2);         // packed a_src/a_dst x3

  dim3 b256(256);
  const int MB = NPAD / 128;  // 391

  detect_dtype<<<dim3(1), dim3(64), 0, stream>>>(Wn, dflag);

  // weight conversion (LDS-tiled transpose to [n][k], bf16; coalesced both sides)
  convert_wt_t<<<dim3(16, 2),  b256, 0, stream>>>(W1, WT1, 64, 512, 0, dflag);
  convert_wt_t<<<dim3(16, 16), b256, 0, stream>>>(W2, WT2, 512, 512, 0, dflag);
  convert_wt_t<<<dim3(16, 16), b256, 0, stream>>>(W3, WT3, 512, 512, 0, dflag);
  convert_wt_t<<<dim3(8, 2),   b256, 0, stream>>>(Wm1, WTPQ,            64, 256, 0,  dflag);
  convert_wt_t<<<dim3(8, 2),   b256, 0, stream>>>(Wm1, WTPQ + 256 * 64, 64, 256, 72, dflag);
  convert_att<<<dim3(12),  b256, 0, stream>>>(as1, ad1, as2, ad2, as3, ad3, attv, dflag);

  // CSR build
  init_deg<<<dim3((N_NODES + 255) / 256), b256, 0, stream>>>(deg, fillc);
  count_edges<<<dim3((N_EDGES + 255) / 256), b256, 0, stream>>>(ei, deg);
  scan1024<<<dim3(1), dim3(1024), 0, stream>>>(deg, rowptr);
  fill_csr<<<dim3((EPRIME + 255) / 256), b256, 0, stream>>>(ei, rowptr, fillc, csr_src);

  // node encoder
  encode_h<<<dim3((N_NODES * 64 + 255) / 256), b256, 0, stream>>>(x, Wn, bn, h_bf, dflag);

  // ---- GAT layer 1 (in: h_bf [NPAD,64]); attn fused in gemm epilogue ----
  gemm_bt<<<dim3(MB, 4), b256, 0, stream>>>(h_bf, WT1, g_bf, 64, 512,
                                            attv, asrc, adst);
  aggregate2<<<dim3(N_NODES), b256, 0, stream>>>(rowptr, csr_src, asrc, adst, sumv,
                                                 g_bf, x, Wr, br, bc1, o_bf, 0,
                                                 nullptr, nullptr, d_out, dflag);

  // ---- GAT layer 2 ----
  gemm_bt<<<dim3(MB, 4), b256, 0, stream>>>(o_bf, WT2, g_bf, 512, 512,
                                            attv + 1024, asrc, adst);
  aggregate2<<<dim3(N_NODES), b256, 0, stream>>>(rowptr, csr_src, asrc, adst, sumv,
                                                 g_bf, x, Wr, br, bc2, o_bf, 0,
                                                 nullptr, nullptr, d_out, dflag);

  // ---- GAT layer 3 (mean over heads -> ne in h_bf; node head fused) ----
  gemm_bt<<<dim3(MB, 4), b256, 0, stream>>>(o_bf, WT3, g_bf, 512, 512,
                                            attv + 2048, asrc, adst);
  aggregate2<<<dim3(N_NODES), b256, 0, stream>>>(rowptr, csr_src, asrc, adst, sumv,
                                                 g_bf, x, Wr, br, bc3, h_bf, 1,
                                                 Wo, bo, d_out, dflag);

  // ---- edge head: P|Q in one gemm, then per-edge MLP (pipelined, packed) ----
  gemm_bt<<<dim3(MB, 4), b256, 0, stream>>>(h_bf, WTPQ, g_bf, 64, 512,
                                            nullptr, nullptr, nullptr);
  edge_head8<<<dim3(N_EDGES / (EPW * 4)), b256, 0, stream>>>(ei, asrc, adst, sumv, g_bf,
                                                             Wm1, bm1, Wm2, bm2,
                                                             d_out, dflag);
}